// Round 1
// baseline (1143.237 us; speedup 1.0000x reference)
//
#include <hip/hip_runtime.h>
#include <hip/hip_bf16.h>
#include <cmath>

#define N 512
#define C_S 384
#define C_Z 128
#define C_H 16
#define H 12
#define PQ 4
#define PV 8

// workspace layout (floats)
// q: 512*192, k: 512*192, v: 512*192, q_pts: 512*144, k_pts: 512*144, v_pts: 512*288
#define WS_Q    0
#define WS_K    (WS_Q + N*H*C_H)
#define WS_V    (WS_K + N*H*C_H)
#define WS_QP   (WS_V + N*H*C_H)
#define WS_KP   (WS_QP + N*H*PQ*3)
#define WS_VP   (WS_KP + N*H*PQ*3)

// ---------------------------------------------------------------------------
// Kernel 1: projections + rotary + point transforms. One block per residue n.
// ---------------------------------------------------------------------------
__global__ __launch_bounds__(256) void k_proj(
    const float* __restrict__ s, const float* __restrict__ rot,
    const float* __restrict__ trans,
    const float* __restrict__ Wq,  const float* __restrict__ bq,
    const float* __restrict__ Wkv, const float* __restrict__ bkv,
    const float* __restrict__ Wqp, const float* __restrict__ bqp,
    const float* __restrict__ Wkvp,const float* __restrict__ bkvp,
    float* __restrict__ ws)
{
    const int n = blockIdx.x;
    const int t = threadIdx.x;
    __shared__ float ssm[C_S];
    __shared__ float raw[1152];   // [0,192) q | [192,576) kv | [576,720) qp | [720,1152) kvp

    for (int idx = t; idx < C_S; idx += 256) ssm[idx] = s[n*C_S + idx];
    __syncthreads();

    for (int col = t; col < 1152; col += 256) {
        const float* W; const float* bias; int c, ncol;
        if (col < 192)      { W = Wq;   bias = bq;   c = col;       ncol = 192; }
        else if (col < 576) { W = Wkv;  bias = bkv;  c = col - 192; ncol = 384; }
        else if (col < 720) { W = Wqp;  bias = bqp;  c = col - 576; ncol = 144; }
        else                { W = Wkvp; bias = bkvp; c = col - 720; ncol = 432; }
        float acc = bias[c];
        for (int r = 0; r < C_S; ++r) acc += ssm[r] * W[r*ncol + c];
        raw[col] = acc;
    }
    __syncthreads();

    float R[9], T[3];
#pragma unroll
    for (int u = 0; u < 9; ++u) R[u] = rot[n*9 + u];
#pragma unroll
    for (int u = 0; u < 3; ++u) T[u] = trans[n*3 + u];

    float* q  = ws + WS_Q;
    float* k  = ws + WS_K;
    float* v  = ws + WS_V;
    float* qp = ws + WS_QP;
    float* kp = ws + WS_KP;
    float* vp = ws + WS_VP;

    for (int idx = t; idx < 1152; idx += 256) {
        if (idx < 192) {
            // q with rotary (rot_dim = 8 per head)
            int h = idx >> 4, c = idx & 15;
            float val;
            if (c < 8) {
                int f = c >> 1;
                float x1 = raw[h*16 + 2*f];
                float x2 = raw[h*16 + 2*f + 1];
                float ang = (float)n * powf(10000.0f, -(float)(2*f) / 8.0f);
                float cs = cosf(ang), sn = sinf(ang);
                val = (c & 1) ? (x1*sn + x2*cs) : (x1*cs - x2*sn);
            } else {
                val = raw[h*16 + c];
            }
            q[n*192 + idx] = val;
        } else if (idx < 384) {
            // k with rotary
            int o = idx - 192, h = o >> 4, c = o & 15;
            float val;
            if (c < 8) {
                int f = c >> 1;
                float x1 = raw[192 + h*32 + 2*f];
                float x2 = raw[192 + h*32 + 2*f + 1];
                float ang = (float)n * powf(10000.0f, -(float)(2*f) / 8.0f);
                float cs = cosf(ang), sn = sinf(ang);
                val = (c & 1) ? (x1*sn + x2*cs) : (x1*cs - x2*sn);
            } else {
                val = raw[192 + h*32 + c];
            }
            k[n*192 + o] = val;
        } else if (idx < 576) {
            // v (no rotary)
            int o = idx - 384, h = o >> 4, c = o & 15;
            v[n*192 + o] = raw[192 + h*32 + 16 + c];
        } else if (idx < 720) {
            // q_pts: o = (h*4+p)*3 + ic ; raw chunk layout: raw[576 + j*48 + (h*4+p)]
            int o = idx - 576;
            int hp = o / 3, ic = o - hp*3;
            float acc = T[ic];
#pragma unroll
            for (int j = 0; j < 3; ++j) acc += R[ic*3 + j] * raw[576 + j*48 + hp];
            qp[n*144 + o] = acc;
        } else {
            // kv_pts: o = (h*12+p)*3 + ic ; raw[720 + j*144 + (h*12+p)]
            int o = idx - 720;
            int hp = o / 3, ic = o - hp*3;
            int h = hp / 12, p = hp - h*12;
            float acc = T[ic];
#pragma unroll
            for (int j = 0; j < 3; ++j) acc += R[ic*3 + j] * raw[720 + j*144 + hp];
            if (p < PQ) kp[n*144 + (h*PQ + p)*3 + ic] = acc;
            else        vp[n*(H*PV*3) + (h*PV + (p - PQ))*3 + ic] = acc;
        }
    }
}

// ---------------------------------------------------------------------------
// Kernel 2: attention logits + softmax. One block per query i. Writes a to d_out.
// ---------------------------------------------------------------------------
__global__ __launch_bounds__(256) void k_score(
    const float* __restrict__ ws, const float* __restrict__ z,
    const float* __restrict__ Wb, const float* __restrict__ bb,
    const float* __restrict__ hwts, const float* __restrict__ mask,
    float* __restrict__ a_out)
{
    const int i = blockIdx.x;
    const int t = threadIdx.x;

    __shared__ float wbT[H*C_Z];      // [h][c]
    __shared__ float qi[H*C_H];
    __shared__ float qpi[H*PQ*3];
    __shared__ float lg[H*N];         // logits, 24 KB
    __shared__ float hw_eff[H];
    __shared__ float bbs[H];

    const float* q  = ws + WS_Q;
    const float* k  = ws + WS_K;
    const float* qp = ws + WS_QP;
    const float* kp = ws + WS_KP;

    for (int idx = t; idx < H*C_Z; idx += 256) {
        int h = idx >> 7, c = idx & 127;
        wbT[idx] = Wb[c*H + h];
    }
    for (int idx = t; idx < H*C_H; idx += 256) qi[idx]  = q[i*192 + idx];
    for (int idx = t; idx < H*PQ*3; idx += 256) qpi[idx] = qp[i*144 + idx];
    if (t < H) {
        hw_eff[t] = log1pf(expf(hwts[t])) * sqrtf(1.0f / 54.0f);
        bbs[t] = bb[t];
    }
    __syncthreads();

    const float c1 = sqrtf(1.0f / 48.0f);
    const float c2 = sqrtf(1.0f / 3.0f);
    const float maskI = mask[i];

    for (int j = t; j < N; j += 256) {
        float acc[H];
#pragma unroll
        for (int h = 0; h < H; ++h) acc[h] = 0.0f;
        // z @ Wb  (the big read)
        const float4* z4 = (const float4*)(z + ((size_t)i*N + j)*C_Z);
#pragma unroll 4
        for (int u = 0; u < C_Z/4; ++u) {
            float4 zv = z4[u];
#pragma unroll
            for (int h = 0; h < H; ++h) {
                const float* wb = &wbT[h*C_Z + u*4];
                acc[h] += zv.x*wb[0] + zv.y*wb[1] + zv.z*wb[2] + zv.w*wb[3];
            }
        }
        const float mterm = 100000.0f * (maskI * mask[j] - 1.0f);
#pragma unroll
        for (int h = 0; h < H; ++h) {
            float qk = 0.0f;
            const float* kj = &k[j*192 + h*16];
            const float* qh = &qi[h*16];
#pragma unroll
            for (int c = 0; c < C_H; ++c) qk += qh[c] * kj[c];
            float d2s = 0.0f;
            const float* kpj = &kp[j*144 + h*12];
            const float* qph = &qpi[h*12];
#pragma unroll
            for (int p = 0; p < PQ; ++p) {
                float dx = qph[p*3+0] - kpj[p*3+0];
                float dy = qph[p*3+1] - kpj[p*3+1];
                float dz = qph[p*3+2] - kpj[p*3+2];
                d2s += dx*dx + dy*dy + dz*dz;
            }
            lg[h*N + j] = c1*qk + c2*(acc[h] + bbs[h]) - 0.5f*hw_eff[h]*d2s + mterm;
        }
    }
    __syncthreads();

    // softmax over j, wave w handles heads w, w+4, w+8
    const int wave = t >> 6, lane = t & 63;
    for (int h = wave; h < H; h += 4) {
        float m = -1e30f;
        for (int j = lane; j < N; j += 64) m = fmaxf(m, lg[h*N + j]);
#pragma unroll
        for (int off = 32; off; off >>= 1) m = fmaxf(m, __shfl_xor(m, off));
        float ssum = 0.0f;
        for (int j = lane; j < N; j += 64) ssum += expf(lg[h*N + j] - m);
#pragma unroll
        for (int off = 32; off; off >>= 1) ssum += __shfl_xor(ssum, off);
        float inv = 1.0f / ssum;
        for (int j = lane; j < N; j += 64)
            a_out[((size_t)h*N + i)*N + j] = expf(lg[h*N + j] - m) * inv;
    }
}

// ---------------------------------------------------------------------------
// Kernel 3: o = a@v, o_pt = a@v_pts, o_pair = a@z, inverse frame, norms,
// fused final projection. One block per query i.
// ---------------------------------------------------------------------------
__global__ __launch_bounds__(256) void k_out(
    const float* __restrict__ a_full, const float* __restrict__ ws,
    const float* __restrict__ z,
    const float* __restrict__ rot, const float* __restrict__ trans,
    const float* __restrict__ Whid, const float* __restrict__ bhid,
    const float* __restrict__ Wpair,const float* __restrict__ bpair,
    const float* __restrict__ Wpts, const float* __restrict__ bpts,
    const float* __restrict__ Wpn,  const float* __restrict__ bpn,
    float* __restrict__ s_out)
{
    const int i = blockIdx.x;
    const int t = threadIdx.x;

    __shared__ float as[H*N];        // 24 KB
    __shared__ float opair[H*C_Z];   // 6 KB
    __shared__ float o_l[H*C_H];
    __shared__ float opt[H*PV*3];
    __shared__ float ptsf[3*H*PV];
    __shared__ float pnorm[H*PV];

    const float* v  = ws + WS_V;
    const float* vp = ws + WS_VP;

    for (int idx = t; idx < H*N; idx += 256) {
        int h = idx >> 9, j = idx & 511;
        as[idx] = a_full[((size_t)h*N + i)*N + j];
    }
    __syncthreads();

    // o and o_pt
    for (int idx = t; idx < 480; idx += 256) {
        if (idx < 192) {
            int h = idx >> 4;
            float acc = 0.0f;
            for (int j = 0; j < N; ++j) acc += as[h*N + j] * v[j*192 + idx];
            o_l[idx] = acc;
        } else {
            int o = idx - 192;
            int hp = o / 3;
            int h = hp >> 3;
            float acc = 0.0f;
            for (int j = 0; j < N; ++j) acc += as[h*N + j] * vp[j*288 + o];
            opt[o] = acc;
        }
    }

    // o_pair = a @ z[i]  (second big z read)
    {
        int c = t & 127, hb = t >> 7;   // hb in {0,1}; heads hb, hb+2, ..., hb+10
        float acc[6];
#pragma unroll
        for (int u = 0; u < 6; ++u) acc[u] = 0.0f;
        const float* zi = z + (size_t)i*N*C_Z;
        for (int j = 0; j < N; ++j) {
            float zv = zi[j*C_Z + c];
#pragma unroll
            for (int u = 0; u < 6; ++u) acc[u] += as[(hb + 2*u)*N + j] * zv;
        }
#pragma unroll
        for (int u = 0; u < 6; ++u) opair[(hb + 2*u)*C_Z + c] = acc[u];
    }
    __syncthreads();

    // inverse frame rotation + pts_feat + norms
    {
        float R[9], T[3];
#pragma unroll
        for (int u = 0; u < 9; ++u) R[u] = rot[i*9 + u];
#pragma unroll
        for (int u = 0; u < 3; ++u) T[u] = trans[i*3 + u];
        for (int hp = t; hp < H*PV; hp += 256) {
            float px = opt[hp*3+0] - T[0];
            float py = opt[hp*3+1] - T[1];
            float pz = opt[hp*3+2] - T[2];
            // out[ic] = sum_j rot[j][ic] * p[j]   (rot transpose)
            float ox = R[0]*px + R[3]*py + R[6]*pz;
            float oy = R[1]*px + R[4]*py + R[7]*pz;
            float oz = R[2]*px + R[5]*py + R[8]*pz;
            ptsf[hp]       = ox;
            ptsf[96 + hp]  = oy;
            ptsf[192 + hp] = oz;
            pnorm[hp] = sqrtf(ox*ox + oy*oy + oz*oz + 1e-8f);
        }
    }
    __syncthreads();

    // fused final projection
    for (int c = t; c < C_S; c += 256) {
        float acc = bhid[c] + bpair[c] + bpts[c] + bpn[c];
        for (int r = 0; r < 192;  ++r) acc += o_l[r]   * Whid[r*C_S + c];
        for (int r = 0; r < 1536; ++r) acc += opair[r] * Wpair[r*C_S + c];
        for (int r = 0; r < 288;  ++r) acc += ptsf[r]  * Wpts[r*C_S + c];
        for (int r = 0; r < 96;   ++r) acc += pnorm[r] * Wpn[r*C_S + c];
        s_out[i*C_S + c] = acc;
    }
}

extern "C" void kernel_launch(void* const* d_in, const int* in_sizes, int n_in,
                              void* d_out, int out_size, void* d_ws, size_t ws_size,
                              hipStream_t stream) {
    const float* s     = (const float*)d_in[0];
    const float* z     = (const float*)d_in[1];
    const float* rot   = (const float*)d_in[2];
    const float* trans = (const float*)d_in[3];
    const float* mask  = (const float*)d_in[4];
    const float* Wq    = (const float*)d_in[5];
    const float* bq    = (const float*)d_in[6];
    const float* Wkv   = (const float*)d_in[7];
    const float* bkv   = (const float*)d_in[8];
    const float* Wqp   = (const float*)d_in[9];
    const float* bqp   = (const float*)d_in[10];
    const float* Wkvp  = (const float*)d_in[11];
    const float* bkvp  = (const float*)d_in[12];
    const float* Wb    = (const float*)d_in[13];
    const float* bb    = (const float*)d_in[14];
    const float* hwts  = (const float*)d_in[15];
    const float* Whid  = (const float*)d_in[16];
    const float* bhid  = (const float*)d_in[17];
    const float* Wpair = (const float*)d_in[18];
    const float* bpair = (const float*)d_in[19];
    const float* Wpts  = (const float*)d_in[20];
    const float* bpts  = (const float*)d_in[21];
    const float* Wpn   = (const float*)d_in[22];
    const float* bpn   = (const float*)d_in[23];

    float* out   = (float*)d_out;
    float* s_out = out;                 // 512*384
    float* a_out = out + N*C_S;         // 12*512*512
    float* ws    = (float*)d_ws;

    k_proj<<<N, 256, 0, stream>>>(s, rot, trans, Wq, bq, Wkv, bkv, Wqp, bqp,
                                  Wkvp, bkvp, ws);
    k_score<<<N, 256, 0, stream>>>(ws, z, Wb, bb, hwts, mask, a_out);
    k_out<<<N, 256, 0, stream>>>(a_out, ws, z, rot, trans,
                                 Whid, bhid, Wpair, bpair, Wpts, bpts, Wpn, bpn,
                                 s_out);
}

// Round 2
// 440.091 us; speedup vs baseline: 2.5977x; 2.5977x over previous
//
#include <hip/hip_runtime.h>
#include <hip/hip_bf16.h>
#include <cmath>

#define N 512
#define C_S 384
#define C_Z 128
#define C_H 16
#define H 12
#define PQ 4
#define PV 8

#define NJC 4            // j-split chunks in k_av
#define JCHUNK (N / NJC) // 128
#define NPART 2016       // per (i,jc) partial vector: o(192) + o_pt(288) + o_pair(1536)
#define NFEAT 2112       // o(192) + o_pair(1536) + ptsf(288) + pnorm(96)

// workspace layout (floats)
#define WS_Q    0
#define WS_K    (WS_Q + N*H*C_H)
#define WS_V    (WS_K + N*H*C_H)
#define WS_QP   (WS_V + N*H*C_H)
#define WS_KP   (WS_QP + N*H*PQ*3)
#define WS_VP   (WS_KP + N*H*PQ*3)
#define WS_PART (WS_VP + N*H*PV*3)            // 512*4*2016 floats
#define WS_FEAT (WS_PART + N*NJC*NPART)       // 512*2112 floats

// ---------------------------------------------------------------------------
// Kernel 1: projections + rotary + point transforms. One block per residue n.
// ---------------------------------------------------------------------------
__global__ __launch_bounds__(256) void k_proj(
    const float* __restrict__ s, const float* __restrict__ rot,
    const float* __restrict__ trans,
    const float* __restrict__ Wq,  const float* __restrict__ bq,
    const float* __restrict__ Wkv, const float* __restrict__ bkv,
    const float* __restrict__ Wqp, const float* __restrict__ bqp,
    const float* __restrict__ Wkvp,const float* __restrict__ bkvp,
    float* __restrict__ ws)
{
    const int n = blockIdx.x;
    const int t = threadIdx.x;
    __shared__ float ssm[C_S];
    __shared__ float raw[1152];   // [0,192) q | [192,576) kv | [576,720) qp | [720,1152) kvp

    for (int idx = t; idx < C_S; idx += 256) ssm[idx] = s[n*C_S + idx];
    __syncthreads();

    for (int col = t; col < 1152; col += 256) {
        const float* W; const float* bias; int c, ncol;
        if (col < 192)      { W = Wq;   bias = bq;   c = col;       ncol = 192; }
        else if (col < 576) { W = Wkv;  bias = bkv;  c = col - 192; ncol = 384; }
        else if (col < 720) { W = Wqp;  bias = bqp;  c = col - 576; ncol = 144; }
        else                { W = Wkvp; bias = bkvp; c = col - 720; ncol = 432; }
        float acc = bias[c];
#pragma unroll 4
        for (int r = 0; r < C_S; ++r) acc += ssm[r] * W[r*ncol + c];
        raw[col] = acc;
    }
    __syncthreads();

    float R[9], T[3];
#pragma unroll
    for (int u = 0; u < 9; ++u) R[u] = rot[n*9 + u];
#pragma unroll
    for (int u = 0; u < 3; ++u) T[u] = trans[n*3 + u];

    float* q  = ws + WS_Q;
    float* k  = ws + WS_K;
    float* v  = ws + WS_V;
    float* qp = ws + WS_QP;
    float* kp = ws + WS_KP;
    float* vp = ws + WS_VP;

    for (int idx = t; idx < 1152; idx += 256) {
        if (idx < 192) {
            int h = idx >> 4, c = idx & 15;
            float val;
            if (c < 8) {
                int f = c >> 1;
                float x1 = raw[h*16 + 2*f];
                float x2 = raw[h*16 + 2*f + 1];
                float ang = (float)n * powf(10000.0f, -(float)(2*f) / 8.0f);
                float cs = cosf(ang), sn = sinf(ang);
                val = (c & 1) ? (x1*sn + x2*cs) : (x1*cs - x2*sn);
            } else {
                val = raw[h*16 + c];
            }
            q[n*192 + idx] = val;
        } else if (idx < 384) {
            int o = idx - 192, h = o >> 4, c = o & 15;
            float val;
            if (c < 8) {
                int f = c >> 1;
                float x1 = raw[192 + h*32 + 2*f];
                float x2 = raw[192 + h*32 + 2*f + 1];
                float ang = (float)n * powf(10000.0f, -(float)(2*f) / 8.0f);
                float cs = cosf(ang), sn = sinf(ang);
                val = (c & 1) ? (x1*sn + x2*cs) : (x1*cs - x2*sn);
            } else {
                val = raw[192 + h*32 + c];
            }
            k[n*192 + o] = val;
        } else if (idx < 576) {
            int o = idx - 384, h = o >> 4, c = o & 15;
            v[n*192 + o] = raw[192 + h*32 + 16 + c];
        } else if (idx < 720) {
            int o = idx - 576;
            int hp = o / 3, ic = o - hp*3;
            float acc = T[ic];
#pragma unroll
            for (int j = 0; j < 3; ++j) acc += R[ic*3 + j] * raw[576 + j*48 + hp];
            qp[n*144 + o] = acc;
        } else {
            int o = idx - 720;
            int hp = o / 3, ic = o - hp*3;
            int h = hp / 12, p = hp - h*12;
            float acc = T[ic];
#pragma unroll
            for (int j = 0; j < 3; ++j) acc += R[ic*3 + j] * raw[720 + j*144 + hp];
            if (p < PQ) kp[n*144 + (h*PQ + p)*3 + ic] = acc;
            else        vp[n*(H*PV*3) + (h*PV + (p - PQ))*3 + ic] = acc;
        }
    }
}

// ---------------------------------------------------------------------------
// Kernel 2: attention logits + softmax. One block per query i. Writes a to d_out.
// ---------------------------------------------------------------------------
__global__ __launch_bounds__(256) void k_score(
    const float* __restrict__ ws, const float* __restrict__ z,
    const float* __restrict__ Wb, const float* __restrict__ bb,
    const float* __restrict__ hwts, const float* __restrict__ mask,
    float* __restrict__ a_out)
{
    const int i = blockIdx.x;
    const int t = threadIdx.x;

    __shared__ float wbT[H*C_Z];
    __shared__ float qi[H*C_H];
    __shared__ float qpi[H*PQ*3];
    __shared__ float lg[H*N];
    __shared__ float hw_eff[H];
    __shared__ float bbs[H];

    const float* q  = ws + WS_Q;
    const float* k  = ws + WS_K;
    const float* qp = ws + WS_QP;
    const float* kp = ws + WS_KP;

    for (int idx = t; idx < H*C_Z; idx += 256) {
        int h = idx >> 7, c = idx & 127;
        wbT[idx] = Wb[c*H + h];
    }
    for (int idx = t; idx < H*C_H; idx += 256) qi[idx]  = q[i*192 + idx];
    for (int idx = t; idx < H*PQ*3; idx += 256) qpi[idx] = qp[i*144 + idx];
    if (t < H) {
        hw_eff[t] = log1pf(expf(hwts[t])) * sqrtf(1.0f / 54.0f);
        bbs[t] = bb[t];
    }
    __syncthreads();

    const float c1 = sqrtf(1.0f / 48.0f);
    const float c2 = sqrtf(1.0f / 3.0f);
    const float maskI = mask[i];

    for (int j = t; j < N; j += 256) {
        float acc[H];
#pragma unroll
        for (int h = 0; h < H; ++h) acc[h] = 0.0f;
        const float4* z4 = (const float4*)(z + ((size_t)i*N + j)*C_Z);
#pragma unroll 4
        for (int u = 0; u < C_Z/4; ++u) {
            float4 zv = z4[u];
#pragma unroll
            for (int h = 0; h < H; ++h) {
                const float* wb = &wbT[h*C_Z + u*4];
                acc[h] += zv.x*wb[0] + zv.y*wb[1] + zv.z*wb[2] + zv.w*wb[3];
            }
        }
        const float mterm = 100000.0f * (maskI * mask[j] - 1.0f);
#pragma unroll
        for (int h = 0; h < H; ++h) {
            float qk = 0.0f;
            const float* kj = &k[j*192 + h*16];
            const float* qh = &qi[h*16];
#pragma unroll
            for (int c = 0; c < C_H; ++c) qk += qh[c] * kj[c];
            float d2s = 0.0f;
            const float* kpj = &kp[j*144 + h*12];
            const float* qph = &qpi[h*12];
#pragma unroll
            for (int p = 0; p < PQ; ++p) {
                float dx = qph[p*3+0] - kpj[p*3+0];
                float dy = qph[p*3+1] - kpj[p*3+1];
                float dz = qph[p*3+2] - kpj[p*3+2];
                d2s += dx*dx + dy*dy + dz*dz;
            }
            lg[h*N + j] = c1*qk + c2*(acc[h] + bbs[h]) - 0.5f*hw_eff[h]*d2s + mterm;
        }
    }
    __syncthreads();

    const int wave = t >> 6, lane = t & 63;
    for (int h = wave; h < H; h += 4) {
        float m = -1e30f;
        for (int j = lane; j < N; j += 64) m = fmaxf(m, lg[h*N + j]);
#pragma unroll
        for (int off = 32; off; off >>= 1) m = fmaxf(m, __shfl_xor(m, off));
        float ssum = 0.0f;
        for (int j = lane; j < N; j += 64) ssum += expf(lg[h*N + j] - m);
#pragma unroll
        for (int off = 32; off; off >>= 1) ssum += __shfl_xor(ssum, off);
        float inv = 1.0f / ssum;
        for (int j = lane; j < N; j += 64)
            a_out[((size_t)h*N + i)*N + j] = expf(lg[h*N + j] - m) * inv;
    }
}

// ---------------------------------------------------------------------------
// Kernel 3a: partial o / o_pt / o_pair over a j-chunk. Grid (N, NJC).
// partial vector layout e: [0,192)=o, [192,480)=o_pt, [480,2016)=o_pair
// ---------------------------------------------------------------------------
__global__ __launch_bounds__(256) void k_av(
    const float* __restrict__ a_full, const float* __restrict__ ws_ro,
    const float* __restrict__ z, float* __restrict__ ws)
{
    const int i  = blockIdx.x;
    const int jc = blockIdx.y;
    const int j0 = jc * JCHUNK;
    const int t  = threadIdx.x;

    __shared__ float a_s[H*JCHUNK];   // 6 KB

    const float* v  = ws_ro + WS_V;
    const float* vp = ws_ro + WS_VP;
    float* part = ws + WS_PART + ((size_t)i*NJC + jc)*NPART;

    for (int e = t; e < H*JCHUNK; e += 256) {
        int h = e >> 7, jj = e & (JCHUNK-1);
        a_s[e] = a_full[((size_t)h*N + i)*N + j0 + jj];
    }
    __syncthreads();

    // Phase A: o (192) and o_pt (288)
    for (int idx = t; idx < 480; idx += 256) {
        float acc = 0.0f;
        if (idx < 192) {
            int h = idx >> 4;
            const float* vv = v + (size_t)j0*192 + idx;
            const float* ar = &a_s[h*JCHUNK];
#pragma unroll 4
            for (int jj = 0; jj < JCHUNK; ++jj) acc += ar[jj] * vv[(size_t)jj*192];
        } else {
            int o = idx - 192;
            int h = (o/3) >> 3;
            const float* vv = vp + (size_t)j0*288 + o;
            const float* ar = &a_s[h*JCHUNK];
#pragma unroll 4
            for (int jj = 0; jj < JCHUNK; ++jj) acc += ar[jj] * vv[(size_t)jj*288];
        }
        part[idx] = acc;
    }

    // Phase B: o_pair (1536). thread -> (hb = t>>7 in {0,1}, c = t&127)
    {
        const int c  = t & 127;
        const int hb = t >> 7;
        float acc[6];
#pragma unroll
        for (int u = 0; u < 6; ++u) acc[u] = 0.0f;
        const float* zi = z + ((size_t)i*N + j0)*C_Z + c;
#pragma unroll 4
        for (int jj = 0; jj < JCHUNK; ++jj) {
            float zv = zi[(size_t)jj*C_Z];
#pragma unroll
            for (int u = 0; u < 6; ++u) acc[u] += a_s[(hb + 2*u)*JCHUNK + jj] * zv;
        }
#pragma unroll
        for (int u = 0; u < 6; ++u) part[480 + (hb + 2*u)*C_Z + c] = acc[u];
    }
}

// ---------------------------------------------------------------------------
// Kernel 3b: reduce partials, inverse-frame rotation, norms -> feat[i][2112].
// feat layout: [0,192)=o, [192,1728)=o_pair, [1728,2016)=ptsf(x|y|z), [2016,2112)=pnorm
// ---------------------------------------------------------------------------
__global__ __launch_bounds__(256) void k_feat(
    const float* __restrict__ rot, const float* __restrict__ trans,
    float* __restrict__ ws)
{
    const int i = blockIdx.x;
    const int t = threadIdx.x;

    __shared__ float vec[NPART];

    const float* part = ws + WS_PART + (size_t)i*NJC*NPART;
    float* feat = ws + WS_FEAT + (size_t)i*NFEAT;

    for (int e = t; e < NPART; e += 256) {
        float acc = 0.0f;
#pragma unroll
        for (int jc = 0; jc < NJC; ++jc) acc += part[(size_t)jc*NPART + e];
        vec[e] = acc;
    }
    __syncthreads();

    for (int e = t; e < NPART; e += 256) {
        if (e < 192)       feat[e] = vec[e];
        else if (e >= 480) feat[192 + (e - 480)] = vec[e];
    }

    if (t < H*PV) {
        const int hp = t;
        float T0 = trans[i*3+0], T1 = trans[i*3+1], T2 = trans[i*3+2];
        float px = vec[192 + hp*3 + 0] - T0;
        float py = vec[192 + hp*3 + 1] - T1;
        float pz = vec[192 + hp*3 + 2] - T2;
        const float* R = rot + i*9;
        float ox = R[0]*px + R[3]*py + R[6]*pz;
        float oy = R[1]*px + R[4]*py + R[7]*pz;
        float oz = R[2]*px + R[5]*py + R[8]*pz;
        feat[1728 + hp]       = ox;
        feat[1728 + 96 + hp]  = oy;
        feat[1728 + 192 + hp] = oz;
        feat[2016 + hp] = sqrtf(ox*ox + oy*oy + oz*oz + 1e-8f);
    }
}

// ---------------------------------------------------------------------------
// Kernel 3c: s_out = feat @ Wcat + biases. Tiled GEMM, M=512 K=2112 N=384.
// Block tile 16m x 64c, KT=32. Grid (32, 6). Thread: tc=t&63, tm=t>>6;
// owns rows m = tm*4 + 0..3.
// ---------------------------------------------------------------------------
__global__ __launch_bounds__(256) void k_final(
    const float* __restrict__ ws,
    const float* __restrict__ Whid, const float* __restrict__ bhid,
    const float* __restrict__ Wpair,const float* __restrict__ bpair,
    const float* __restrict__ Wpts, const float* __restrict__ bpts,
    const float* __restrict__ Wpn,  const float* __restrict__ bpn,
    float* __restrict__ s_out)
{
    const int m0 = blockIdx.x * 16;
    const int c0 = blockIdx.y * 64;
    const int t  = threadIdx.x;
    const int tc = t & 63;
    const int tm = t >> 6;

    __shared__ float wt[32*64];    // [k][c]
    __shared__ float ftT[32*16];   // [k][m]

    const float* feat = ws + WS_FEAT;

    const int c = c0 + tc;
    float acc[4];
    {
        float b = bhid[c] + bpair[c] + bpts[c] + bpn[c];
#pragma unroll
        for (int r = 0; r < 4; ++r) acc[r] = b;
    }

    for (int k0 = 0; k0 < NFEAT; k0 += 32) {
        const float* W; int r0;
        if (k0 < 192)       { W = Whid;  r0 = k0; }
        else if (k0 < 1728) { W = Wpair; r0 = k0 - 192; }
        else if (k0 < 2016) { W = Wpts;  r0 = k0 - 1728; }
        else                { W = Wpn;   r0 = k0 - 2016; }

        __syncthreads();
        for (int e = t; e < 2048; e += 256) {
            int kk = e >> 6, cc = e & 63;
            wt[kk*64 + cc] = W[(size_t)(r0 + kk)*C_S + c0 + cc];
        }
        for (int e = t; e < 512; e += 256) {
            int m = e >> 5, kk = e & 31;
            ftT[kk*16 + m] = feat[(size_t)(m0 + m)*NFEAT + k0 + kk];
        }
        __syncthreads();

        const float4* ftT4 = (const float4*)ftT;
#pragma unroll
        for (int kk = 0; kk < 32; ++kk) {
            float4 f = ftT4[kk*4 + tm];
            float w = wt[kk*64 + tc];
            acc[0] += f.x * w;
            acc[1] += f.y * w;
            acc[2] += f.z * w;
            acc[3] += f.w * w;
        }
    }

#pragma unroll
    for (int r = 0; r < 4; ++r)
        s_out[(size_t)(m0 + tm*4 + r)*C_S + c] = acc[r];
}

extern "C" void kernel_launch(void* const* d_in, const int* in_sizes, int n_in,
                              void* d_out, int out_size, void* d_ws, size_t ws_size,
                              hipStream_t stream) {
    const float* s     = (const float*)d_in[0];
    const float* z     = (const float*)d_in[1];
    const float* rot   = (const float*)d_in[2];
    const float* trans = (const float*)d_in[3];
    const float* mask  = (const float*)d_in[4];
    const float* Wq    = (const float*)d_in[5];
    const float* bq    = (const float*)d_in[6];
    const float* Wkv   = (const float*)d_in[7];
    const float* bkv   = (const float*)d_in[8];
    const float* Wqp   = (const float*)d_in[9];
    const float* bqp   = (const float*)d_in[10];
    const float* Wkvp  = (const float*)d_in[11];
    const float* bkvp  = (const float*)d_in[12];
    const float* Wb    = (const float*)d_in[13];
    const float* bb    = (const float*)d_in[14];
    const float* hwts  = (const float*)d_in[15];
    const float* Whid  = (const float*)d_in[16];
    const float* bhid  = (const float*)d_in[17];
    const float* Wpair = (const float*)d_in[18];
    const float* bpair = (const float*)d_in[19];
    const float* Wpts  = (const float*)d_in[20];
    const float* bpts  = (const float*)d_in[21];
    const float* Wpn   = (const float*)d_in[22];
    const float* bpn   = (const float*)d_in[23];

    float* out   = (float*)d_out;
    float* s_out = out;                 // 512*384
    float* a_out = out + N*C_S;         // 12*512*512
    float* ws    = (float*)d_ws;

    k_proj<<<N, 256, 0, stream>>>(s, rot, trans, Wq, bq, Wkv, bkv, Wqp, bqp,
                                  Wkvp, bkvp, ws);
    k_score<<<N, 256, 0, stream>>>(ws, z, Wb, bb, hwts, mask, a_out);
    k_av<<<dim3(N, NJC), 256, 0, stream>>>(a_out, ws, z, ws);
    k_feat<<<N, 256, 0, stream>>>(rot, trans, ws);
    k_final<<<dim3(32, 6), 256, 0, stream>>>(ws, Whid, bhid, Wpair, bpair,
                                             Wpts, bpts, Wpn, bpn, s_out);
}

// Round 3
// 338.032 us; speedup vs baseline: 3.3820x; 1.3019x over previous
//
#include <hip/hip_runtime.h>
#include <hip/hip_bf16.h>
#include <cmath>

#define N 512
#define C_S 384
#define C_Z 128
#define C_H 16
#define H 12
#define PQ 4
#define PV 8

#define NJC 4            // j-split chunks in k_av
#define JCHUNK (N / NJC) // 128
#define NPART 2016       // per (i,jc) partial vector: o(192) + o_pt(288) + o_pair(1536)
#define NFEAT 2112       // o(192) + o_pair(1536) + ptsf(288) + pnorm(96)
#define NRAW 1152        // q(192) + kv(384) + qp(144) + kvp(432)

// workspace layout (floats)
#define WS_Q    0
#define WS_K    (WS_Q + N*H*C_H)
#define WS_V    (WS_K + N*H*C_H)
#define WS_QP   (WS_V + N*H*C_H)
#define WS_KP   (WS_QP + N*H*PQ*3)
#define WS_VP   (WS_KP + N*H*PQ*3)
#define WS_PART (WS_VP + N*H*PV*3)            // 512*4*2016 floats (raw projections alias here first)
#define WS_FEAT (WS_PART + N*NJC*NPART)       // 512*2112 floats
#define WS_RAW  WS_PART                       // raw[512][1152], consumed by k_post before k_av runs

// ---------------------------------------------------------------------------
// Kernel 1a: raw projections as one tiled GEMM.
// raw[n][col] = s[n] . Wcat[:,col] + bcat[col],  col layout:
// [0,192)=Wq | [192,576)=Wkv | [576,720)=Wqp | [720,1152)=Wkvp
// Grid (8, 18), block 256. Tile 64m x 64c, KT=32. Thread: tc=t&15, tm=t>>4,
// owns rows m0+tm*4+0..3, cols c0+tc*4+0..3.
// ---------------------------------------------------------------------------
__global__ __launch_bounds__(256) void k_gemm_proj(
    const float* __restrict__ s,
    const float* __restrict__ Wq,  const float* __restrict__ bq,
    const float* __restrict__ Wkv, const float* __restrict__ bkv,
    const float* __restrict__ Wqp, const float* __restrict__ bqp,
    const float* __restrict__ Wkvp,const float* __restrict__ bkvp,
    float* __restrict__ raw_out)
{
    const int m0 = blockIdx.x * 64;
    const int c0 = blockIdx.y * 64;
    const int t  = threadIdx.x;
    const int tc = t & 15;
    const int tm = t >> 4;

    __shared__ float st[64 * 33];   // [m][kk], pad 33 -> 2-way max on reads
    __shared__ float wt[32 * 64];   // [kk][c]

    float acc[4][4];
#pragma unroll
    for (int u = 0; u < 4; ++u) {
        int col = c0 + tc*4 + u;
        const float* b; int cb;
        if (col < 192)      { b = bq;   cb = 0; }
        else if (col < 576) { b = bkv;  cb = 192; }
        else if (col < 720) { b = bqp;  cb = 576; }
        else                { b = bkvp; cb = 720; }
        float bv = b[col - cb];
#pragma unroll
        for (int r = 0; r < 4; ++r) acc[r][u] = bv;
    }

    for (int k0 = 0; k0 < C_S; k0 += 32) {
        __syncthreads();
        // stage s tile: 64 rows x 32 k, coalesced float4 along k
        for (int e = t; e < 512; e += 256) {
            int row = e >> 3, kq = e & 7;
            float4 v = *(const float4*)&s[(size_t)(m0 + row)*C_S + k0 + kq*4];
            st[row*33 + kq*4 + 0] = v.x;
            st[row*33 + kq*4 + 1] = v.y;
            st[row*33 + kq*4 + 2] = v.z;
            st[row*33 + kq*4 + 3] = v.w;
        }
        // stage W tile: 32 k x 64 c, float4 along c with per-chunk matrix select
        for (int e = t; e < 512; e += 256) {
            int kk = e >> 4, c4 = e & 15;
            int col = c0 + c4*4;
            const float* W; int ncol, cb;
            if (col < 192)      { W = Wq;   ncol = 192; cb = 0; }
            else if (col < 576) { W = Wkv;  ncol = 384; cb = 192; }
            else if (col < 720) { W = Wqp;  ncol = 144; cb = 576; }
            else                { W = Wkvp; ncol = 432; cb = 720; }
            float4 v = *(const float4*)&W[(size_t)(k0 + kk)*ncol + (col - cb)];
            *(float4*)&wt[kk*64 + c4*4] = v;
        }
        __syncthreads();

#pragma unroll 8
        for (int kk = 0; kk < 32; ++kk) {
            float4 w = *(const float4*)&wt[kk*64 + tc*4];
            float sv[4];
#pragma unroll
            for (int r = 0; r < 4; ++r) sv[r] = st[(tm*4 + r)*33 + kk];
#pragma unroll
            for (int r = 0; r < 4; ++r) {
                acc[r][0] += sv[r] * w.x;
                acc[r][1] += sv[r] * w.y;
                acc[r][2] += sv[r] * w.z;
                acc[r][3] += sv[r] * w.w;
            }
        }
    }

#pragma unroll
    for (int r = 0; r < 4; ++r) {
        float4 o = make_float4(acc[r][0], acc[r][1], acc[r][2], acc[r][3]);
        *(float4*)&raw_out[(size_t)(m0 + tm*4 + r)*NRAW + c0 + tc*4] = o;
    }
}

// ---------------------------------------------------------------------------
// Kernel 1b: rotary + rigid-frame point transforms. One block per residue n.
// ---------------------------------------------------------------------------
__global__ __launch_bounds__(256) void k_post(
    const float* __restrict__ raw_in, const float* __restrict__ rot,
    const float* __restrict__ trans, float* __restrict__ ws)
{
    const int n = blockIdx.x;
    const int t = threadIdx.x;
    __shared__ float raw[NRAW];

    for (int idx = t; idx < NRAW; idx += 256) raw[idx] = raw_in[(size_t)n*NRAW + idx];
    __syncthreads();

    float R[9], T[3];
#pragma unroll
    for (int u = 0; u < 9; ++u) R[u] = rot[n*9 + u];
#pragma unroll
    for (int u = 0; u < 3; ++u) T[u] = trans[n*3 + u];

    float* q  = ws + WS_Q;
    float* k  = ws + WS_K;
    float* v  = ws + WS_V;
    float* qp = ws + WS_QP;
    float* kp = ws + WS_KP;
    float* vp = ws + WS_VP;

    for (int idx = t; idx < 1152; idx += 256) {
        if (idx < 192) {
            int h = idx >> 4, c = idx & 15;
            float val;
            if (c < 8) {
                int f = c >> 1;
                float x1 = raw[h*16 + 2*f];
                float x2 = raw[h*16 + 2*f + 1];
                float ang = (float)n * powf(10000.0f, -(float)(2*f) / 8.0f);
                float cs = cosf(ang), sn = sinf(ang);
                val = (c & 1) ? (x1*sn + x2*cs) : (x1*cs - x2*sn);
            } else {
                val = raw[h*16 + c];
            }
            q[n*192 + idx] = val;
        } else if (idx < 384) {
            int o = idx - 192, h = o >> 4, c = o & 15;
            float val;
            if (c < 8) {
                int f = c >> 1;
                float x1 = raw[192 + h*32 + 2*f];
                float x2 = raw[192 + h*32 + 2*f + 1];
                float ang = (float)n * powf(10000.0f, -(float)(2*f) / 8.0f);
                float cs = cosf(ang), sn = sinf(ang);
                val = (c & 1) ? (x1*sn + x2*cs) : (x1*cs - x2*sn);
            } else {
                val = raw[192 + h*32 + c];
            }
            k[n*192 + o] = val;
        } else if (idx < 576) {
            int o = idx - 384, h = o >> 4, c = o & 15;
            v[n*192 + o] = raw[192 + h*32 + 16 + c];
        } else if (idx < 720) {
            int o = idx - 576;
            int hp = o / 3, ic = o - hp*3;
            float acc = T[ic];
#pragma unroll
            for (int j = 0; j < 3; ++j) acc += R[ic*3 + j] * raw[576 + j*48 + hp];
            qp[n*144 + o] = acc;
        } else {
            int o = idx - 720;
            int hp = o / 3, ic = o - hp*3;
            int h = hp / 12, p = hp - h*12;
            float acc = T[ic];
#pragma unroll
            for (int j = 0; j < 3; ++j) acc += R[ic*3 + j] * raw[720 + j*144 + hp];
            if (p < PQ) kp[n*144 + (h*PQ + p)*3 + ic] = acc;
            else        vp[n*(H*PV*3) + (h*PV + (p - PQ))*3 + ic] = acc;
        }
    }
}

// ---------------------------------------------------------------------------
// Kernel 2: attention logits + softmax. One block per query i. Writes a to d_out.
// ---------------------------------------------------------------------------
__global__ __launch_bounds__(256) void k_score(
    const float* __restrict__ ws, const float* __restrict__ z,
    const float* __restrict__ Wb, const float* __restrict__ bb,
    const float* __restrict__ hwts, const float* __restrict__ mask,
    float* __restrict__ a_out)
{
    const int i = blockIdx.x;
    const int t = threadIdx.x;

    __shared__ float wbT[H*C_Z];
    __shared__ float qi[H*C_H];
    __shared__ float qpi[H*PQ*3];
    __shared__ float lg[H*N];
    __shared__ float hw_eff[H];
    __shared__ float bbs[H];

    const float* q  = ws + WS_Q;
    const float* k  = ws + WS_K;
    const float* qp = ws + WS_QP;
    const float* kp = ws + WS_KP;

    for (int idx = t; idx < H*C_Z; idx += 256) {
        int h = idx >> 7, c = idx & 127;
        wbT[idx] = Wb[c*H + h];
    }
    for (int idx = t; idx < H*C_H; idx += 256) qi[idx]  = q[i*192 + idx];
    for (int idx = t; idx < H*PQ*3; idx += 256) qpi[idx] = qp[i*144 + idx];
    if (t < H) {
        hw_eff[t] = log1pf(expf(hwts[t])) * sqrtf(1.0f / 54.0f);
        bbs[t] = bb[t];
    }
    __syncthreads();

    const float c1 = sqrtf(1.0f / 48.0f);
    const float c2 = sqrtf(1.0f / 3.0f);
    const float maskI = mask[i];

    for (int j = t; j < N; j += 256) {
        float acc[H];
#pragma unroll
        for (int h = 0; h < H; ++h) acc[h] = 0.0f;
        const float4* z4 = (const float4*)(z + ((size_t)i*N + j)*C_Z);
#pragma unroll 4
        for (int u = 0; u < C_Z/4; ++u) {
            float4 zv = z4[u];
#pragma unroll
            for (int h = 0; h < H; ++h) {
                const float* wb = &wbT[h*C_Z + u*4];
                acc[h] += zv.x*wb[0] + zv.y*wb[1] + zv.z*wb[2] + zv.w*wb[3];
            }
        }
        const float mterm = 100000.0f * (maskI * mask[j] - 1.0f);
#pragma unroll
        for (int h = 0; h < H; ++h) {
            float qk = 0.0f;
            const float* kj = &k[j*192 + h*16];
            const float* qh = &qi[h*16];
#pragma unroll
            for (int c = 0; c < C_H; ++c) qk += qh[c] * kj[c];
            float d2s = 0.0f;
            const float* kpj = &kp[j*144 + h*12];
            const float* qph = &qpi[h*12];
#pragma unroll
            for (int p = 0; p < PQ; ++p) {
                float dx = qph[p*3+0] - kpj[p*3+0];
                float dy = qph[p*3+1] - kpj[p*3+1];
                float dz = qph[p*3+2] - kpj[p*3+2];
                d2s += dx*dx + dy*dy + dz*dz;
            }
            lg[h*N + j] = c1*qk + c2*(acc[h] + bbs[h]) - 0.5f*hw_eff[h]*d2s + mterm;
        }
    }
    __syncthreads();

    const int wave = t >> 6, lane = t & 63;
    for (int h = wave; h < H; h += 4) {
        float m = -1e30f;
        for (int j = lane; j < N; j += 64) m = fmaxf(m, lg[h*N + j]);
#pragma unroll
        for (int off = 32; off; off >>= 1) m = fmaxf(m, __shfl_xor(m, off));
        float ssum = 0.0f;
        for (int j = lane; j < N; j += 64) ssum += expf(lg[h*N + j] - m);
#pragma unroll
        for (int off = 32; off; off >>= 1) ssum += __shfl_xor(ssum, off);
        float inv = 1.0f / ssum;
        for (int j = lane; j < N; j += 64)
            a_out[((size_t)h*N + i)*N + j] = expf(lg[h*N + j] - m) * inv;
    }
}

// ---------------------------------------------------------------------------
// Kernel 3a: partial o / o_pt / o_pair over a j-chunk. Grid (N, NJC).
// partial vector layout e: [0,192)=o, [192,480)=o_pt, [480,2016)=o_pair
// ---------------------------------------------------------------------------
__global__ __launch_bounds__(256) void k_av(
    const float* __restrict__ a_full, const float* __restrict__ ws_ro,
    const float* __restrict__ z, float* __restrict__ ws)
{
    const int i  = blockIdx.x;
    const int jc = blockIdx.y;
    const int j0 = jc * JCHUNK;
    const int t  = threadIdx.x;

    __shared__ float a_s[H*JCHUNK];   // 6 KB

    const float* v  = ws_ro + WS_V;
    const float* vp = ws_ro + WS_VP;
    float* part = ws + WS_PART + ((size_t)i*NJC + jc)*NPART;

    for (int e = t; e < H*JCHUNK; e += 256) {
        int h = e >> 7, jj = e & (JCHUNK-1);
        a_s[e] = a_full[((size_t)h*N + i)*N + j0 + jj];
    }
    __syncthreads();

    // Phase A: o (192) and o_pt (288)
    for (int idx = t; idx < 480; idx += 256) {
        float acc = 0.0f;
        if (idx < 192) {
            int h = idx >> 4;
            const float* vv = v + (size_t)j0*192 + idx;
            const float* ar = &a_s[h*JCHUNK];
#pragma unroll 4
            for (int jj = 0; jj < JCHUNK; ++jj) acc += ar[jj] * vv[(size_t)jj*192];
        } else {
            int o = idx - 192;
            int h = (o/3) >> 3;
            const float* vv = vp + (size_t)j0*288 + o;
            const float* ar = &a_s[h*JCHUNK];
#pragma unroll 4
            for (int jj = 0; jj < JCHUNK; ++jj) acc += ar[jj] * vv[(size_t)jj*288];
        }
        part[idx] = acc;
    }

    // Phase B: o_pair (1536). thread -> (hb = t>>7 in {0,1}, c = t&127)
    {
        const int c  = t & 127;
        const int hb = t >> 7;
        float acc[6];
#pragma unroll
        for (int u = 0; u < 6; ++u) acc[u] = 0.0f;
        const float* zi = z + ((size_t)i*N + j0)*C_Z + c;
#pragma unroll 4
        for (int jj = 0; jj < JCHUNK; ++jj) {
            float zv = zi[(size_t)jj*C_Z];
#pragma unroll
            for (int u = 0; u < 6; ++u) acc[u] += a_s[(hb + 2*u)*JCHUNK + jj] * zv;
        }
#pragma unroll
        for (int u = 0; u < 6; ++u) part[480 + (hb + 2*u)*C_Z + c] = acc[u];
    }
}

// ---------------------------------------------------------------------------
// Kernel 3b: reduce partials, inverse-frame rotation, norms -> feat[i][2112].
// feat layout: [0,192)=o, [192,1728)=o_pair, [1728,2016)=ptsf(x|y|z), [2016,2112)=pnorm
// ---------------------------------------------------------------------------
__global__ __launch_bounds__(256) void k_feat(
    const float* __restrict__ rot, const float* __restrict__ trans,
    float* __restrict__ ws)
{
    const int i = blockIdx.x;
    const int t = threadIdx.x;

    __shared__ float vec[NPART];

    const float* part = ws + WS_PART + (size_t)i*NJC*NPART;
    float* feat = ws + WS_FEAT + (size_t)i*NFEAT;

    for (int e = t; e < NPART; e += 256) {
        float acc = 0.0f;
#pragma unroll
        for (int jc = 0; jc < NJC; ++jc) acc += part[(size_t)jc*NPART + e];
        vec[e] = acc;
    }
    __syncthreads();

    for (int e = t; e < NPART; e += 256) {
        if (e < 192)       feat[e] = vec[e];
        else if (e >= 480) feat[192 + (e - 480)] = vec[e];
    }

    if (t < H*PV) {
        const int hp = t;
        float T0 = trans[i*3+0], T1 = trans[i*3+1], T2 = trans[i*3+2];
        float px = vec[192 + hp*3 + 0] - T0;
        float py = vec[192 + hp*3 + 1] - T1;
        float pz = vec[192 + hp*3 + 2] - T2;
        const float* R = rot + i*9;
        float ox = R[0]*px + R[3]*py + R[6]*pz;
        float oy = R[1]*px + R[4]*py + R[7]*pz;
        float oz = R[2]*px + R[5]*py + R[8]*pz;
        feat[1728 + hp]       = ox;
        feat[1728 + 96 + hp]  = oy;
        feat[1728 + 192 + hp] = oz;
        feat[2016 + hp] = sqrtf(ox*ox + oy*oy + oz*oz + 1e-8f);
    }
}

// ---------------------------------------------------------------------------
// Kernel 3c: s_out = feat @ Wcat + biases. Tiled GEMM, M=512 K=2112 N=384.
// ---------------------------------------------------------------------------
__global__ __launch_bounds__(256) void k_final(
    const float* __restrict__ ws,
    const float* __restrict__ Whid, const float* __restrict__ bhid,
    const float* __restrict__ Wpair,const float* __restrict__ bpair,
    const float* __restrict__ Wpts, const float* __restrict__ bpts,
    const float* __restrict__ Wpn,  const float* __restrict__ bpn,
    float* __restrict__ s_out)
{
    const int m0 = blockIdx.x * 16;
    const int c0 = blockIdx.y * 64;
    const int t  = threadIdx.x;
    const int tc = t & 63;
    const int tm = t >> 6;

    __shared__ float wt[32*64];    // [k][c]
    __shared__ float ftT[32*16];   // [k][m]

    const float* feat = ws + WS_FEAT;

    const int c = c0 + tc;
    float acc[4];
    {
        float b = bhid[c] + bpair[c] + bpts[c] + bpn[c];
#pragma unroll
        for (int r = 0; r < 4; ++r) acc[r] = b;
    }

    for (int k0 = 0; k0 < NFEAT; k0 += 32) {
        const float* W; int r0;
        if (k0 < 192)       { W = Whid;  r0 = k0; }
        else if (k0 < 1728) { W = Wpair; r0 = k0 - 192; }
        else if (k0 < 2016) { W = Wpts;  r0 = k0 - 1728; }
        else                { W = Wpn;   r0 = k0 - 2016; }

        __syncthreads();
        for (int e = t; e < 2048; e += 256) {
            int kk = e >> 6, cc = e & 63;
            wt[kk*64 + cc] = W[(size_t)(r0 + kk)*C_S + c0 + cc];
        }
        for (int e = t; e < 512; e += 256) {
            int m = e >> 5, kk = e & 31;
            ftT[kk*16 + m] = feat[(size_t)(m0 + m)*NFEAT + k0 + kk];
        }
        __syncthreads();

        const float4* ftT4 = (const float4*)ftT;
#pragma unroll
        for (int kk = 0; kk < 32; ++kk) {
            float4 f = ftT4[kk*4 + tm];
            float w = wt[kk*64 + tc];
            acc[0] += f.x * w;
            acc[1] += f.y * w;
            acc[2] += f.z * w;
            acc[3] += f.w * w;
        }
    }

#pragma unroll
    for (int r = 0; r < 4; ++r)
        s_out[(size_t)(m0 + tm*4 + r)*C_S + c] = acc[r];
}

extern "C" void kernel_launch(void* const* d_in, const int* in_sizes, int n_in,
                              void* d_out, int out_size, void* d_ws, size_t ws_size,
                              hipStream_t stream) {
    const float* s     = (const float*)d_in[0];
    const float* z     = (const float*)d_in[1];
    const float* rot   = (const float*)d_in[2];
    const float* trans = (const float*)d_in[3];
    const float* mask  = (const float*)d_in[4];
    const float* Wq    = (const float*)d_in[5];
    const float* bq    = (const float*)d_in[6];
    const float* Wkv   = (const float*)d_in[7];
    const float* bkv   = (const float*)d_in[8];
    const float* Wqp   = (const float*)d_in[9];
    const float* bqp   = (const float*)d_in[10];
    const float* Wkvp  = (const float*)d_in[11];
    const float* bkvp  = (const float*)d_in[12];
    const float* Wb    = (const float*)d_in[13];
    const float* bb    = (const float*)d_in[14];
    const float* hwts  = (const float*)d_in[15];
    const float* Whid  = (const float*)d_in[16];
    const float* bhid  = (const float*)d_in[17];
    const float* Wpair = (const float*)d_in[18];
    const float* bpair = (const float*)d_in[19];
    const float* Wpts  = (const float*)d_in[20];
    const float* bpts  = (const float*)d_in[21];
    const float* Wpn   = (const float*)d_in[22];
    const float* bpn   = (const float*)d_in[23];

    float* out   = (float*)d_out;
    float* s_out = out;                 // 512*384
    float* a_out = out + N*C_S;         // 12*512*512
    float* ws    = (float*)d_ws;

    k_gemm_proj<<<dim3(8, 18), 256, 0, stream>>>(s, Wq, bq, Wkv, bkv, Wqp, bqp,
                                                 Wkvp, bkvp, ws + WS_RAW);
    k_post<<<N, 256, 0, stream>>>(ws + WS_RAW, rot, trans, ws);
    k_score<<<N, 256, 0, stream>>>(ws, z, Wb, bb, hwts, mask, a_out);
    k_av<<<dim3(N, NJC), 256, 0, stream>>>(a_out, ws, z, ws);
    k_feat<<<N, 256, 0, stream>>>(rot, trans, ws);
    k_final<<<dim3(32, 6), 256, 0, stream>>>(ws, Whid, bhid, Wpair, bpair,
                                             Wpts, bpts, Wpn, bpn, s_out);
}

// Round 4
// 211.509 us; speedup vs baseline: 5.4052x; 1.5982x over previous
//
#include <hip/hip_runtime.h>
#include <hip/hip_bf16.h>
#include <cmath>

#define N 512
#define C_S 384
#define C_Z 128
#define C_H 16
#define H 12
#define PQ 4
#define PV 8

#define NJC 4            // j-split chunks in k_av
#define JCHUNK (N / NJC) // 128
#define NPART 2016       // per (i,jc) partial vector: o(192) + o_pt(288) + o_pair(1536)
#define NFEAT 2112       // o(192) + o_pair(1536) + ptsf(288) + pnorm(96)
#define NRAW 1152        // q(192) + kv(384) + qp(144) + kvp(432)
#define KSPLIT 11        // k-chunks in k_final_part (2112 = 11*192)
#define KCHUNK 192

// workspace layout (floats)
#define WS_Q    0
#define WS_K    (WS_Q + N*H*C_H)
#define WS_V    (WS_K + N*H*C_H)
#define WS_QP   (WS_V + N*H*C_H)
#define WS_KP   (WS_QP + N*H*PQ*3)
#define WS_VP   (WS_KP + N*H*PQ*3)
#define WS_PART (WS_VP + N*H*PV*3)            // 512*4*2016 floats
#define WS_FEAT (WS_PART + N*NJC*NPART)       // 512*2112 floats
#define WS_RAW  WS_PART                       // raw[512][1152]; dead before k_av writes partials
#define WS_FOUT WS_PART                       // fout[11][512][384]; dead after k_feat

// ---------------------------------------------------------------------------
// Kernel 1a: raw projections as one tiled GEMM.
// ---------------------------------------------------------------------------
__global__ __launch_bounds__(256) void k_gemm_proj(
    const float* __restrict__ s,
    const float* __restrict__ Wq,  const float* __restrict__ bq,
    const float* __restrict__ Wkv, const float* __restrict__ bkv,
    const float* __restrict__ Wqp, const float* __restrict__ bqp,
    const float* __restrict__ Wkvp,const float* __restrict__ bkvp,
    float* __restrict__ raw_out)
{
    const int m0 = blockIdx.x * 64;
    const int c0 = blockIdx.y * 64;
    const int t  = threadIdx.x;
    const int tc = t & 15;
    const int tm = t >> 4;

    __shared__ float st[64 * 33];
    __shared__ float wt[32 * 64];

    float acc[4][4];
#pragma unroll
    for (int u = 0; u < 4; ++u) {
        int col = c0 + tc*4 + u;
        const float* b; int cb;
        if (col < 192)      { b = bq;   cb = 0; }
        else if (col < 576) { b = bkv;  cb = 192; }
        else if (col < 720) { b = bqp;  cb = 576; }
        else                { b = bkvp; cb = 720; }
        float bv = b[col - cb];
#pragma unroll
        for (int r = 0; r < 4; ++r) acc[r][u] = bv;
    }

    for (int k0 = 0; k0 < C_S; k0 += 32) {
        __syncthreads();
        for (int e = t; e < 512; e += 256) {
            int row = e >> 3, kq = e & 7;
            float4 v = *(const float4*)&s[(size_t)(m0 + row)*C_S + k0 + kq*4];
            st[row*33 + kq*4 + 0] = v.x;
            st[row*33 + kq*4 + 1] = v.y;
            st[row*33 + kq*4 + 2] = v.z;
            st[row*33 + kq*4 + 3] = v.w;
        }
        for (int e = t; e < 512; e += 256) {
            int kk = e >> 4, c4 = e & 15;
            int col = c0 + c4*4;
            const float* W; int ncol, cb;
            if (col < 192)      { W = Wq;   ncol = 192; cb = 0; }
            else if (col < 576) { W = Wkv;  ncol = 384; cb = 192; }
            else if (col < 720) { W = Wqp;  ncol = 144; cb = 576; }
            else                { W = Wkvp; ncol = 432; cb = 720; }
            float4 v = *(const float4*)&W[(size_t)(k0 + kk)*ncol + (col - cb)];
            *(float4*)&wt[kk*64 + c4*4] = v;
        }
        __syncthreads();

#pragma unroll 8
        for (int kk = 0; kk < 32; ++kk) {
            float4 w = *(const float4*)&wt[kk*64 + tc*4];
            float sv[4];
#pragma unroll
            for (int r = 0; r < 4; ++r) sv[r] = st[(tm*4 + r)*33 + kk];
#pragma unroll
            for (int r = 0; r < 4; ++r) {
                acc[r][0] += sv[r] * w.x;
                acc[r][1] += sv[r] * w.y;
                acc[r][2] += sv[r] * w.z;
                acc[r][3] += sv[r] * w.w;
            }
        }
    }

#pragma unroll
    for (int r = 0; r < 4; ++r) {
        float4 o = make_float4(acc[r][0], acc[r][1], acc[r][2], acc[r][3]);
        *(float4*)&raw_out[(size_t)(m0 + tm*4 + r)*NRAW + c0 + tc*4] = o;
    }
}

// ---------------------------------------------------------------------------
// Kernel 1b: rotary + rigid-frame point transforms. One block per residue n.
// ---------------------------------------------------------------------------
__global__ __launch_bounds__(256) void k_post(
    const float* __restrict__ raw_in, const float* __restrict__ rot,
    const float* __restrict__ trans, float* __restrict__ ws)
{
    const int n = blockIdx.x;
    const int t = threadIdx.x;
    __shared__ float raw[NRAW];

    for (int idx = t; idx < NRAW; idx += 256) raw[idx] = raw_in[(size_t)n*NRAW + idx];
    __syncthreads();

    float R[9], T[3];
#pragma unroll
    for (int u = 0; u < 9; ++u) R[u] = rot[n*9 + u];
#pragma unroll
    for (int u = 0; u < 3; ++u) T[u] = trans[n*3 + u];

    float* q  = ws + WS_Q;
    float* k  = ws + WS_K;
    float* v  = ws + WS_V;
    float* qp = ws + WS_QP;
    float* kp = ws + WS_KP;
    float* vp = ws + WS_VP;

    for (int idx = t; idx < 1152; idx += 256) {
        if (idx < 192) {
            int h = idx >> 4, c = idx & 15;
            float val;
            if (c < 8) {
                int f = c >> 1;
                float x1 = raw[h*16 + 2*f];
                float x2 = raw[h*16 + 2*f + 1];
                float ang = (float)n * powf(10000.0f, -(float)(2*f) / 8.0f);
                float cs = cosf(ang), sn = sinf(ang);
                val = (c & 1) ? (x1*sn + x2*cs) : (x1*cs - x2*sn);
            } else {
                val = raw[h*16 + c];
            }
            q[n*192 + idx] = val;
        } else if (idx < 384) {
            int o = idx - 192, h = o >> 4, c = o & 15;
            float val;
            if (c < 8) {
                int f = c >> 1;
                float x1 = raw[192 + h*32 + 2*f];
                float x2 = raw[192 + h*32 + 2*f + 1];
                float ang = (float)n * powf(10000.0f, -(float)(2*f) / 8.0f);
                float cs = cosf(ang), sn = sinf(ang);
                val = (c & 1) ? (x1*sn + x2*cs) : (x1*cs - x2*sn);
            } else {
                val = raw[192 + h*32 + c];
            }
            k[n*192 + o] = val;
        } else if (idx < 576) {
            int o = idx - 384, h = o >> 4, c = o & 15;
            v[n*192 + o] = raw[192 + h*32 + 16 + c];
        } else if (idx < 720) {
            int o = idx - 576;
            int hp = o / 3, ic = o - hp*3;
            float acc = T[ic];
#pragma unroll
            for (int j = 0; j < 3; ++j) acc += R[ic*3 + j] * raw[576 + j*48 + hp];
            qp[n*144 + o] = acc;
        } else {
            int o = idx - 720;
            int hp = o / 3, ic = o - hp*3;
            int h = hp / 12, p = hp - h*12;
            float acc = T[ic];
#pragma unroll
            for (int j = 0; j < 3; ++j) acc += R[ic*3 + j] * raw[720 + j*144 + hp];
            if (p < PQ) kp[n*144 + (h*PQ + p)*3 + ic] = acc;
            else        vp[n*(H*PV*3) + (h*PV + (p - PQ))*3 + ic] = acc;
        }
    }
}

// ---------------------------------------------------------------------------
// Kernel 2: attention logits + softmax. One block per query i. Writes a to d_out.
// ---------------------------------------------------------------------------
__global__ __launch_bounds__(256) void k_score(
    const float* __restrict__ ws, const float* __restrict__ z,
    const float* __restrict__ Wb, const float* __restrict__ bb,
    const float* __restrict__ hwts, const float* __restrict__ mask,
    float* __restrict__ a_out)
{
    const int i = blockIdx.x;
    const int t = threadIdx.x;

    __shared__ float wbT[H*C_Z];
    __shared__ float qi[H*C_H];
    __shared__ float qpi[H*PQ*3];
    __shared__ float lg[H*N];
    __shared__ float hw_eff[H];
    __shared__ float bbs[H];

    const float* q  = ws + WS_Q;
    const float* k  = ws + WS_K;
    const float* qp = ws + WS_QP;
    const float* kp = ws + WS_KP;

    for (int idx = t; idx < H*C_Z; idx += 256) {
        int h = idx >> 7, c = idx & 127;
        wbT[idx] = Wb[c*H + h];
    }
    for (int idx = t; idx < H*C_H; idx += 256) qi[idx]  = q[i*192 + idx];
    for (int idx = t; idx < H*PQ*3; idx += 256) qpi[idx] = qp[i*144 + idx];
    if (t < H) {
        hw_eff[t] = log1pf(expf(hwts[t])) * sqrtf(1.0f / 54.0f);
        bbs[t] = bb[t];
    }
    __syncthreads();

    const float c1 = sqrtf(1.0f / 48.0f);
    const float c2 = sqrtf(1.0f / 3.0f);
    const float maskI = mask[i];

    for (int j = t; j < N; j += 256) {
        float acc[H];
#pragma unroll
        for (int h = 0; h < H; ++h) acc[h] = 0.0f;
        const float4* z4 = (const float4*)(z + ((size_t)i*N + j)*C_Z);
#pragma unroll 4
        for (int u = 0; u < C_Z/4; ++u) {
            float4 zv = z4[u];
#pragma unroll
            for (int h = 0; h < H; ++h) {
                const float* wb = &wbT[h*C_Z + u*4];
                acc[h] += zv.x*wb[0] + zv.y*wb[1] + zv.z*wb[2] + zv.w*wb[3];
            }
        }
        const float mterm = 100000.0f * (maskI * mask[j] - 1.0f);
#pragma unroll
        for (int h = 0; h < H; ++h) {
            float qk = 0.0f;
            const float* kj = &k[j*192 + h*16];
            const float* qh = &qi[h*16];
#pragma unroll
            for (int c = 0; c < C_H; ++c) qk += qh[c] * kj[c];
            float d2s = 0.0f;
            const float* kpj = &kp[j*144 + h*12];
            const float* qph = &qpi[h*12];
#pragma unroll
            for (int p = 0; p < PQ; ++p) {
                float dx = qph[p*3+0] - kpj[p*3+0];
                float dy = qph[p*3+1] - kpj[p*3+1];
                float dz = qph[p*3+2] - kpj[p*3+2];
                d2s += dx*dx + dy*dy + dz*dz;
            }
            lg[h*N + j] = c1*qk + c2*(acc[h] + bbs[h]) - 0.5f*hw_eff[h]*d2s + mterm;
        }
    }
    __syncthreads();

    const int wave = t >> 6, lane = t & 63;
    for (int h = wave; h < H; h += 4) {
        float m = -1e30f;
        for (int j = lane; j < N; j += 64) m = fmaxf(m, lg[h*N + j]);
#pragma unroll
        for (int off = 32; off; off >>= 1) m = fmaxf(m, __shfl_xor(m, off));
        float ssum = 0.0f;
        for (int j = lane; j < N; j += 64) ssum += expf(lg[h*N + j] - m);
#pragma unroll
        for (int off = 32; off; off >>= 1) ssum += __shfl_xor(ssum, off);
        float inv = 1.0f / ssum;
        for (int j = lane; j < N; j += 64)
            a_out[((size_t)h*N + i)*N + j] = expf(lg[h*N + j] - m) * inv;
    }
}

// ---------------------------------------------------------------------------
// Kernel 3a: partial o / o_pt / o_pair over a j-chunk. Grid (N, NJC).
// ---------------------------------------------------------------------------
__global__ __launch_bounds__(256) void k_av(
    const float* __restrict__ a_full, const float* __restrict__ ws_ro,
    const float* __restrict__ z, float* __restrict__ ws)
{
    const int i  = blockIdx.x;
    const int jc = blockIdx.y;
    const int j0 = jc * JCHUNK;
    const int t  = threadIdx.x;

    __shared__ float a_s[H*JCHUNK];

    const float* v  = ws_ro + WS_V;
    const float* vp = ws_ro + WS_VP;
    float* part = ws + WS_PART + ((size_t)i*NJC + jc)*NPART;

    for (int e = t; e < H*JCHUNK; e += 256) {
        int h = e >> 7, jj = e & (JCHUNK-1);
        a_s[e] = a_full[((size_t)h*N + i)*N + j0 + jj];
    }
    __syncthreads();

    for (int idx = t; idx < 480; idx += 256) {
        float acc = 0.0f;
        if (idx < 192) {
            int h = idx >> 4;
            const float* vv = v + (size_t)j0*192 + idx;
            const float* ar = &a_s[h*JCHUNK];
#pragma unroll 4
            for (int jj = 0; jj < JCHUNK; ++jj) acc += ar[jj] * vv[(size_t)jj*192];
        } else {
            int o = idx - 192;
            int h = (o/3) >> 3;
            const float* vv = vp + (size_t)j0*288 + o;
            const float* ar = &a_s[h*JCHUNK];
#pragma unroll 4
            for (int jj = 0; jj < JCHUNK; ++jj) acc += ar[jj] * vv[(size_t)jj*288];
        }
        part[idx] = acc;
    }

    {
        const int c  = t & 127;
        const int hb = t >> 7;
        float acc[6];
#pragma unroll
        for (int u = 0; u < 6; ++u) acc[u] = 0.0f;
        const float* zi = z + ((size_t)i*N + j0)*C_Z + c;
#pragma unroll 4
        for (int jj = 0; jj < JCHUNK; ++jj) {
            float zv = zi[(size_t)jj*C_Z];
#pragma unroll
            for (int u = 0; u < 6; ++u) acc[u] += a_s[(hb + 2*u)*JCHUNK + jj] * zv;
        }
#pragma unroll
        for (int u = 0; u < 6; ++u) part[480 + (hb + 2*u)*C_Z + c] = acc[u];
    }
}

// ---------------------------------------------------------------------------
// Kernel 3b: reduce partials, inverse-frame rotation, norms -> feat[i][2112].
// ---------------------------------------------------------------------------
__global__ __launch_bounds__(256) void k_feat(
    const float* __restrict__ rot, const float* __restrict__ trans,
    float* __restrict__ ws)
{
    const int i = blockIdx.x;
    const int t = threadIdx.x;

    __shared__ float vec[NPART];

    const float* part = ws + WS_PART + (size_t)i*NJC*NPART;
    float* feat = ws + WS_FEAT + (size_t)i*NFEAT;

    for (int e = t; e < NPART; e += 256) {
        float acc = 0.0f;
#pragma unroll
        for (int jc = 0; jc < NJC; ++jc) acc += part[(size_t)jc*NPART + e];
        vec[e] = acc;
    }
    __syncthreads();

    for (int e = t; e < NPART; e += 256) {
        if (e < 192)       feat[e] = vec[e];
        else if (e >= 480) feat[192 + (e - 480)] = vec[e];
    }

    if (t < H*PV) {
        const int hp = t;
        float T0 = trans[i*3+0], T1 = trans[i*3+1], T2 = trans[i*3+2];
        float px = vec[192 + hp*3 + 0] - T0;
        float py = vec[192 + hp*3 + 1] - T1;
        float pz = vec[192 + hp*3 + 2] - T2;
        const float* R = rot + i*9;
        float ox = R[0]*px + R[3]*py + R[6]*pz;
        float oy = R[1]*px + R[4]*py + R[7]*pz;
        float oz = R[2]*px + R[5]*py + R[8]*pz;
        feat[1728 + hp]       = ox;
        feat[1728 + 96 + hp]  = oy;
        feat[1728 + 192 + hp] = oz;
        feat[2016 + hp] = sqrtf(ox*ox + oy*oy + oz*oz + 1e-8f);
    }
}

// ---------------------------------------------------------------------------
// Kernel 3c: split-K GEMM partials. Grid (8, 6, KSPLIT). Tile 64m x 64c,
// K-chunk 192 (6 steps of 32). Thread: tc=t&15 (4 cols), tm=t>>4 (4 rows).
// fout[kc][m][c] into WS_FOUT (aliases WS_PART, dead after k_feat).
// ---------------------------------------------------------------------------
__global__ __launch_bounds__(256) void k_final_part(
    const float* __restrict__ ws,
    const float* __restrict__ Whid, const float* __restrict__ Wpair,
    const float* __restrict__ Wpts, const float* __restrict__ Wpn,
    float* __restrict__ fout)
{
    const int m0 = blockIdx.x * 64;
    const int c0 = blockIdx.y * 64;
    const int kc = blockIdx.z;
    const int t  = threadIdx.x;
    const int tc = t & 15;
    const int tm = t >> 4;

    __shared__ float ft[64 * 33];   // [m][kk]
    __shared__ float wt[32 * 64];   // [kk][c]

    const float* feat = ws + WS_FEAT;

    float acc[4][4];
#pragma unroll
    for (int r = 0; r < 4; ++r)
#pragma unroll
        for (int u = 0; u < 4; ++u) acc[r][u] = 0.0f;

    const int kbase = kc * KCHUNK;
    for (int k0 = kbase; k0 < kbase + KCHUNK; k0 += 32) {
        const float* W; int r0;
        if (k0 < 192)       { W = Whid;  r0 = k0; }
        else if (k0 < 1728) { W = Wpair; r0 = k0 - 192; }
        else if (k0 < 2016) { W = Wpts;  r0 = k0 - 1728; }
        else                { W = Wpn;   r0 = k0 - 2016; }

        __syncthreads();
        for (int e = t; e < 512; e += 256) {
            int row = e >> 3, kq = e & 7;
            float4 v = *(const float4*)&feat[(size_t)(m0 + row)*NFEAT + k0 + kq*4];
            ft[row*33 + kq*4 + 0] = v.x;
            ft[row*33 + kq*4 + 1] = v.y;
            ft[row*33 + kq*4 + 2] = v.z;
            ft[row*33 + kq*4 + 3] = v.w;
        }
        for (int e = t; e < 512; e += 256) {
            int kk = e >> 4, c4 = e & 15;
            float4 v = *(const float4*)&W[(size_t)(r0 + kk)*C_S + c0 + c4*4];
            *(float4*)&wt[kk*64 + c4*4] = v;
        }
        __syncthreads();

#pragma unroll 8
        for (int kk = 0; kk < 32; ++kk) {
            float4 w = *(const float4*)&wt[kk*64 + tc*4];
            float sv[4];
#pragma unroll
            for (int r = 0; r < 4; ++r) sv[r] = ft[(tm*4 + r)*33 + kk];
#pragma unroll
            for (int r = 0; r < 4; ++r) {
                acc[r][0] += sv[r] * w.x;
                acc[r][1] += sv[r] * w.y;
                acc[r][2] += sv[r] * w.z;
                acc[r][3] += sv[r] * w.w;
            }
        }
    }

#pragma unroll
    for (int r = 0; r < 4; ++r) {
        float4 o = make_float4(acc[r][0], acc[r][1], acc[r][2], acc[r][3]);
        *(float4*)&fout[((size_t)kc*N + m0 + tm*4 + r)*C_S + c0 + tc*4] = o;
    }
}

// ---------------------------------------------------------------------------
// Kernel 3d: reduce split-K partials + bias -> s_out. 768 blocks x 256.
// ---------------------------------------------------------------------------
__global__ __launch_bounds__(256) void k_red(
    const float* __restrict__ fout,
    const float* __restrict__ bhid, const float* __restrict__ bpair,
    const float* __restrict__ bpts, const float* __restrict__ bpn,
    float* __restrict__ s_out)
{
    const int idx = blockIdx.x * 256 + threadIdx.x;   // 512*384 total
    const int c = idx % C_S;
    float acc = bhid[c] + bpair[c] + bpts[c] + bpn[c];
#pragma unroll
    for (int kc = 0; kc < KSPLIT; ++kc)
        acc += fout[(size_t)kc*N*C_S + idx];
    s_out[idx] = acc;
}

extern "C" void kernel_launch(void* const* d_in, const int* in_sizes, int n_in,
                              void* d_out, int out_size, void* d_ws, size_t ws_size,
                              hipStream_t stream) {
    const float* s     = (const float*)d_in[0];
    const float* z     = (const float*)d_in[1];
    const float* rot   = (const float*)d_in[2];
    const float* trans = (const float*)d_in[3];
    const float* mask  = (const float*)d_in[4];
    const float* Wq    = (const float*)d_in[5];
    const float* bq    = (const float*)d_in[6];
    const float* Wkv   = (const float*)d_in[7];
    const float* bkv   = (const float*)d_in[8];
    const float* Wqp   = (const float*)d_in[9];
    const float* bqp   = (const float*)d_in[10];
    const float* Wkvp  = (const float*)d_in[11];
    const float* bkvp  = (const float*)d_in[12];
    const float* Wb    = (const float*)d_in[13];
    const float* bb    = (const float*)d_in[14];
    const float* hwts  = (const float*)d_in[15];
    const float* Whid  = (const float*)d_in[16];
    const float* bhid  = (const float*)d_in[17];
    const float* Wpair = (const float*)d_in[18];
    const float* bpair = (const float*)d_in[19];
    const float* Wpts  = (const float*)d_in[20];
    const float* bpts  = (const float*)d_in[21];
    const float* Wpn   = (const float*)d_in[22];
    const float* bpn   = (const float*)d_in[23];

    float* out   = (float*)d_out;
    float* s_out = out;                 // 512*384
    float* a_out = out + N*C_S;         // 12*512*512
    float* ws    = (float*)d_ws;

    k_gemm_proj<<<dim3(8, 18), 256, 0, stream>>>(s, Wq, bq, Wkv, bkv, Wqp, bqp,
                                                 Wkvp, bkvp, ws + WS_RAW);
    k_post<<<N, 256, 0, stream>>>(ws + WS_RAW, rot, trans, ws);
    k_score<<<N, 256, 0, stream>>>(ws, z, Wb, bb, hwts, mask, a_out);
    k_av<<<dim3(N, NJC), 256, 0, stream>>>(a_out, ws, z, ws);
    k_feat<<<N, 256, 0, stream>>>(rot, trans, ws);
    k_final_part<<<dim3(8, 6, KSPLIT), 256, 0, stream>>>(ws, Whid, Wpair, Wpts,
                                                         Wpn, ws + WS_FOUT);
    k_red<<<(N*C_S)/256, 256, 0, stream>>>(ws + WS_FOUT, bhid, bpair, bpts, bpn,
                                           s_out);
}

// Round 5
// 207.306 us; speedup vs baseline: 5.5147x; 1.0203x over previous
//
#include <hip/hip_runtime.h>
#include <hip/hip_bf16.h>
#include <cmath>

#define N 512
#define C_S 384
#define C_Z 128
#define C_H 16
#define H 12
#define PQ 4
#define PV 8

#define NJC 4            // j-split chunks in k_av
#define JCHUNK (N / NJC) // 128
#define NPART 2016       // per (i,jc) partial vector: o(192) + o_pt(288) + o_pair(1536)
#define NFEAT 2112       // o(192) + o_pair(1536) + ptsf(288) + pnorm(96)
#define NRAW 1152        // q(192) + kv(384) + qp(144) + kvp(432)
#define KSPLIT 11        // k-chunks in k_final_part (2112 = 11*192)
#define KCHUNK 192

// workspace layout (floats)
#define WS_Q    0
#define WS_K    (WS_Q + N*H*C_H)
#define WS_V    (WS_K + N*H*C_H)
#define WS_QP   (WS_V + N*H*C_H)
#define WS_KP   (WS_QP + N*H*PQ*3)
#define WS_VP   (WS_KP + N*H*PQ*3)
#define WS_PART (WS_VP + N*H*PV*3)            // 512*4*2016 floats
#define WS_FEAT (WS_PART + N*NJC*NPART)       // 512*2112 floats
#define WS_RAW  WS_PART                       // raw[512][1152]; dead before k_av writes partials
#define WS_FOUT WS_PART                       // fout[11][512][384]; dead after k_feat

// ---------------------------------------------------------------------------
// Kernel 1a: raw projections as one tiled GEMM.
// ---------------------------------------------------------------------------
__global__ __launch_bounds__(256) void k_gemm_proj(
    const float* __restrict__ s,
    const float* __restrict__ Wq,  const float* __restrict__ bq,
    const float* __restrict__ Wkv, const float* __restrict__ bkv,
    const float* __restrict__ Wqp, const float* __restrict__ bqp,
    const float* __restrict__ Wkvp,const float* __restrict__ bkvp,
    float* __restrict__ raw_out)
{
    const int m0 = blockIdx.x * 64;
    const int c0 = blockIdx.y * 64;
    const int t  = threadIdx.x;
    const int tc = t & 15;
    const int tm = t >> 4;

    __shared__ float st[64 * 33];
    __shared__ float wt[32 * 64];

    float acc[4][4];
#pragma unroll
    for (int u = 0; u < 4; ++u) {
        int col = c0 + tc*4 + u;
        const float* b; int cb;
        if (col < 192)      { b = bq;   cb = 0; }
        else if (col < 576) { b = bkv;  cb = 192; }
        else if (col < 720) { b = bqp;  cb = 576; }
        else                { b = bkvp; cb = 720; }
        float bv = b[col - cb];
#pragma unroll
        for (int r = 0; r < 4; ++r) acc[r][u] = bv;
    }

    for (int k0 = 0; k0 < C_S; k0 += 32) {
        __syncthreads();
        for (int e = t; e < 512; e += 256) {
            int row = e >> 3, kq = e & 7;
            float4 v = *(const float4*)&s[(size_t)(m0 + row)*C_S + k0 + kq*4];
            st[row*33 + kq*4 + 0] = v.x;
            st[row*33 + kq*4 + 1] = v.y;
            st[row*33 + kq*4 + 2] = v.z;
            st[row*33 + kq*4 + 3] = v.w;
        }
        for (int e = t; e < 512; e += 256) {
            int kk = e >> 4, c4 = e & 15;
            int col = c0 + c4*4;
            const float* W; int ncol, cb;
            if (col < 192)      { W = Wq;   ncol = 192; cb = 0; }
            else if (col < 576) { W = Wkv;  ncol = 384; cb = 192; }
            else if (col < 720) { W = Wqp;  ncol = 144; cb = 576; }
            else                { W = Wkvp; ncol = 432; cb = 720; }
            float4 v = *(const float4*)&W[(size_t)(k0 + kk)*ncol + (col - cb)];
            *(float4*)&wt[kk*64 + c4*4] = v;
        }
        __syncthreads();

#pragma unroll 8
        for (int kk = 0; kk < 32; ++kk) {
            float4 w = *(const float4*)&wt[kk*64 + tc*4];
            float sv[4];
#pragma unroll
            for (int r = 0; r < 4; ++r) sv[r] = st[(tm*4 + r)*33 + kk];
#pragma unroll
            for (int r = 0; r < 4; ++r) {
                acc[r][0] += sv[r] * w.x;
                acc[r][1] += sv[r] * w.y;
                acc[r][2] += sv[r] * w.z;
                acc[r][3] += sv[r] * w.w;
            }
        }
    }

#pragma unroll
    for (int r = 0; r < 4; ++r) {
        float4 o = make_float4(acc[r][0], acc[r][1], acc[r][2], acc[r][3]);
        *(float4*)&raw_out[(size_t)(m0 + tm*4 + r)*NRAW + c0 + tc*4] = o;
    }
}

// ---------------------------------------------------------------------------
// Kernel 1b: rotary + rigid-frame point transforms. One block per residue n.
// ---------------------------------------------------------------------------
__global__ __launch_bounds__(256) void k_post(
    const float* __restrict__ raw_in, const float* __restrict__ rot,
    const float* __restrict__ trans, float* __restrict__ ws)
{
    const int n = blockIdx.x;
    const int t = threadIdx.x;
    __shared__ float raw[NRAW];

    for (int idx = t; idx < NRAW; idx += 256) raw[idx] = raw_in[(size_t)n*NRAW + idx];
    __syncthreads();

    float R[9], T[3];
#pragma unroll
    for (int u = 0; u < 9; ++u) R[u] = rot[n*9 + u];
#pragma unroll
    for (int u = 0; u < 3; ++u) T[u] = trans[n*3 + u];

    float* q  = ws + WS_Q;
    float* k  = ws + WS_K;
    float* v  = ws + WS_V;
    float* qp = ws + WS_QP;
    float* kp = ws + WS_KP;
    float* vp = ws + WS_VP;

    for (int idx = t; idx < 1152; idx += 256) {
        if (idx < 192) {
            int h = idx >> 4, c = idx & 15;
            float val;
            if (c < 8) {
                int f = c >> 1;
                float x1 = raw[h*16 + 2*f];
                float x2 = raw[h*16 + 2*f + 1];
                float ang = (float)n * powf(10000.0f, -(float)(2*f) / 8.0f);
                float cs = cosf(ang), sn = sinf(ang);
                val = (c & 1) ? (x1*sn + x2*cs) : (x1*cs - x2*sn);
            } else {
                val = raw[h*16 + c];
            }
            q[n*192 + idx] = val;
        } else if (idx < 384) {
            int o = idx - 192, h = o >> 4, c = o & 15;
            float val;
            if (c < 8) {
                int f = c >> 1;
                float x1 = raw[192 + h*32 + 2*f];
                float x2 = raw[192 + h*32 + 2*f + 1];
                float ang = (float)n * powf(10000.0f, -(float)(2*f) / 8.0f);
                float cs = cosf(ang), sn = sinf(ang);
                val = (c & 1) ? (x1*sn + x2*cs) : (x1*cs - x2*sn);
            } else {
                val = raw[192 + h*32 + c];
            }
            k[n*192 + o] = val;
        } else if (idx < 576) {
            int o = idx - 384, h = o >> 4, c = o & 15;
            v[n*192 + o] = raw[192 + h*32 + 16 + c];
        } else if (idx < 720) {
            int o = idx - 576;
            int hp = o / 3, ic = o - hp*3;
            float acc = T[ic];
#pragma unroll
            for (int j = 0; j < 3; ++j) acc += R[ic*3 + j] * raw[576 + j*48 + hp];
            qp[n*144 + o] = acc;
        } else {
            int o = idx - 720;
            int hp = o / 3, ic = o - hp*3;
            int h = hp / 12, p = hp - h*12;
            float acc = T[ic];
#pragma unroll
            for (int j = 0; j < 3; ++j) acc += R[ic*3 + j] * raw[720 + j*144 + hp];
            if (p < PQ) kp[n*144 + (h*PQ + p)*3 + ic] = acc;
            else        vp[n*(H*PV*3) + (h*PV + (p - PQ))*3 + ic] = acc;
        }
    }
}

// ---------------------------------------------------------------------------
// Kernel 2a: raw logits. Grid (N, 4): block = (i, 128-j chunk).
// Phase 1: qk + point-dist + mask + const -> qkd LDS.
// Phase 2: z@Wb over 4 subtiles of 32 j, LDS-staged z (pad 129), partials
// reduce in padded LDS, write raw logits to a_out[h][i][j].
// ---------------------------------------------------------------------------
__global__ __launch_bounds__(256) void k_logits(
    const float* __restrict__ ws, const float* __restrict__ z,
    const float* __restrict__ Wb, const float* __restrict__ bb,
    const float* __restrict__ hwts, const float* __restrict__ mask,
    float* __restrict__ a_out)
{
    const int i  = blockIdx.x;
    const int j0 = blockIdx.y * 128;
    const int t  = threadIdx.x;

    __shared__ float zt[32*129];      // z subtile [j][c], pad 129
    __shared__ float part[8*12*33];   // partials [g][h][j], pad 33
    __shared__ float qkd[12*129];     // qk+dist+mask+const [h][j], pad 129
    __shared__ float wbL[H*C_Z];      // Wb transposed [h][c]
    __shared__ float qi[192];
    __shared__ float qpi[144];
    __shared__ float hw_eff[12], bbs[12];

    const float* q  = ws + WS_Q;
    const float* k  = ws + WS_K;
    const float* qp = ws + WS_QP;
    const float* kp = ws + WS_KP;

    for (int idx = t; idx < H*C_Z; idx += 256) {
        int h = idx >> 7, c = idx & 127;
        wbL[idx] = Wb[c*H + h];
    }
    if (t < 192) qi[t]  = q[i*192 + t];
    if (t < 144) qpi[t] = qp[i*144 + t];
    if (t < 12) {
        hw_eff[t] = log1pf(expf(hwts[t])) * sqrtf(1.0f / 54.0f);
        bbs[t]    = bb[t];
    }
    __syncthreads();

    const float c1 = sqrtf(1.0f / 48.0f);
    const float c2 = sqrtf(1.0f / 3.0f);
    const float maskI = mask[i];

    // phase 1: per (j, h) cheap terms
    {
        const int j  = t & 127;
        const int hb = t >> 7;
        const int jg = j0 + j;
        const float mterm = 100000.0f * (maskI * mask[jg] - 1.0f);
        const float* kj  = &k[jg*192];
        const float* kpj = &kp[jg*144];
#pragma unroll
        for (int u = 0; u < 6; ++u) {
            const int h = hb*6 + u;
            float qk = 0.0f;
#pragma unroll
            for (int c = 0; c < 16; ++c) qk += qi[h*16 + c] * kj[h*16 + c];
            float d2s = 0.0f;
#pragma unroll
            for (int p = 0; p < 4; ++p) {
                float dx = qpi[h*12 + p*3 + 0] - kpj[h*12 + p*3 + 0];
                float dy = qpi[h*12 + p*3 + 1] - kpj[h*12 + p*3 + 1];
                float dz = qpi[h*12 + p*3 + 2] - kpj[h*12 + p*3 + 2];
                d2s += dx*dx + dy*dy + dz*dz;
            }
            qkd[h*129 + j] = c1*qk - 0.5f*hw_eff[h]*d2s + mterm + c2*bbs[h];
        }
    }

    // phase 2: z@Wb in 4 subtiles of 32 j
    for (int s = 0; s < 4; ++s) {
        __syncthreads();
        for (int e = t; e < 1024; e += 256) {
            int row = e >> 5, cq = e & 31;
            float4 v = *(const float4*)&z[(((size_t)i*N) + j0 + s*32 + row)*C_Z + cq*4];
            zt[row*129 + cq*4 + 0] = v.x;
            zt[row*129 + cq*4 + 1] = v.y;
            zt[row*129 + cq*4 + 2] = v.z;
            zt[row*129 + cq*4 + 3] = v.w;
        }
        __syncthreads();
        {
            const int j = t & 31, g = t >> 5;
            float acc[12];
#pragma unroll
            for (int h = 0; h < 12; ++h) acc[h] = 0.0f;
            const float* zr = &zt[j*129 + g*16];
            const float* wb = &wbL[g*16];
#pragma unroll
            for (int cc = 0; cc < 16; ++cc) {
                float zv = zr[cc];
#pragma unroll
                for (int h = 0; h < 12; ++h) acc[h] += zv * wb[h*128 + cc];
            }
#pragma unroll
            for (int h = 0; h < 12; ++h) part[g*396 + h*33 + j] = acc[h];
        }
        __syncthreads();
        {
            const int j = t & 31, hh = t >> 5;
            const int jl = s*32 + j;
#pragma unroll
            for (int rep = 0; rep < 2; ++rep) {
                int h = hh + rep*8;
                if (h < 12) {
                    float sum = 0.0f;
#pragma unroll
                    for (int g = 0; g < 8; ++g) sum += part[g*396 + h*33 + j];
                    a_out[((size_t)h*N + i)*N + j0 + jl] = qkd[h*129 + jl] + c2*sum;
                }
            }
        }
    }
}

// ---------------------------------------------------------------------------
// Kernel 2b: in-place softmax over rows of a_out[6144][512]. One wave per row.
// ---------------------------------------------------------------------------
__global__ __launch_bounds__(256) void k_softmax(float* __restrict__ a)
{
    const int row  = blockIdx.x*4 + (threadIdx.x >> 6);
    const int lane = threadIdx.x & 63;
    float* r = a + (size_t)row * N;

    float v[8];
    float m = -1e30f;
#pragma unroll
    for (int u = 0; u < 8; ++u) { v[u] = r[lane + 64*u]; m = fmaxf(m, v[u]); }
#pragma unroll
    for (int off = 32; off; off >>= 1) m = fmaxf(m, __shfl_xor(m, off));
    float ssum = 0.0f;
#pragma unroll
    for (int u = 0; u < 8; ++u) { v[u] = expf(v[u] - m); ssum += v[u]; }
#pragma unroll
    for (int off = 32; off; off >>= 1) ssum += __shfl_xor(ssum, off);
    float inv = 1.0f / ssum;
#pragma unroll
    for (int u = 0; u < 8; ++u) r[lane + 64*u] = v[u] * inv;
}

// ---------------------------------------------------------------------------
// Kernel 3a: partial o / o_pt / o_pair over a j-chunk. Grid (N, NJC).
// ---------------------------------------------------------------------------
__global__ __launch_bounds__(256) void k_av(
    const float* __restrict__ a_full, const float* __restrict__ ws_ro,
    const float* __restrict__ z, float* __restrict__ ws)
{
    const int i  = blockIdx.x;
    const int jc = blockIdx.y;
    const int j0 = jc * JCHUNK;
    const int t  = threadIdx.x;

    __shared__ float a_s[H*JCHUNK];

    const float* v  = ws_ro + WS_V;
    const float* vp = ws_ro + WS_VP;
    float* part = ws + WS_PART + ((size_t)i*NJC + jc)*NPART;

    for (int e = t; e < H*JCHUNK; e += 256) {
        int h = e >> 7, jj = e & (JCHUNK-1);
        a_s[e] = a_full[((size_t)h*N + i)*N + j0 + jj];
    }
    __syncthreads();

    for (int idx = t; idx < 480; idx += 256) {
        float acc = 0.0f;
        if (idx < 192) {
            int h = idx >> 4;
            const float* vv = v + (size_t)j0*192 + idx;
            const float* ar = &a_s[h*JCHUNK];
#pragma unroll 4
            for (int jj = 0; jj < JCHUNK; ++jj) acc += ar[jj] * vv[(size_t)jj*192];
        } else {
            int o = idx - 192;
            int h = (o/3) >> 3;
            const float* vv = vp + (size_t)j0*288 + o;
            const float* ar = &a_s[h*JCHUNK];
#pragma unroll 4
            for (int jj = 0; jj < JCHUNK; ++jj) acc += ar[jj] * vv[(size_t)jj*288];
        }
        part[idx] = acc;
    }

    {
        const int c  = t & 127;
        const int hb = t >> 7;
        float acc[6];
#pragma unroll
        for (int u = 0; u < 6; ++u) acc[u] = 0.0f;
        const float* zi = z + ((size_t)i*N + j0)*C_Z + c;
#pragma unroll 4
        for (int jj = 0; jj < JCHUNK; ++jj) {
            float zv = zi[(size_t)jj*C_Z];
#pragma unroll
            for (int u = 0; u < 6; ++u) acc[u] += a_s[(hb + 2*u)*JCHUNK + jj] * zv;
        }
#pragma unroll
        for (int u = 0; u < 6; ++u) part[480 + (hb + 2*u)*C_Z + c] = acc[u];
    }
}

// ---------------------------------------------------------------------------
// Kernel 3b: reduce partials, inverse-frame rotation, norms -> feat[i][2112].
// ---------------------------------------------------------------------------
__global__ __launch_bounds__(256) void k_feat(
    const float* __restrict__ rot, const float* __restrict__ trans,
    float* __restrict__ ws)
{
    const int i = blockIdx.x;
    const int t = threadIdx.x;

    __shared__ float vec[NPART];

    const float* part = ws + WS_PART + (size_t)i*NJC*NPART;
    float* feat = ws + WS_FEAT + (size_t)i*NFEAT;

    for (int e = t; e < NPART; e += 256) {
        float acc = 0.0f;
#pragma unroll
        for (int jc = 0; jc < NJC; ++jc) acc += part[(size_t)jc*NPART + e];
        vec[e] = acc;
    }
    __syncthreads();

    for (int e = t; e < NPART; e += 256) {
        if (e < 192)       feat[e] = vec[e];
        else if (e >= 480) feat[192 + (e - 480)] = vec[e];
    }

    if (t < H*PV) {
        const int hp = t;
        float T0 = trans[i*3+0], T1 = trans[i*3+1], T2 = trans[i*3+2];
        float px = vec[192 + hp*3 + 0] - T0;
        float py = vec[192 + hp*3 + 1] - T1;
        float pz = vec[192 + hp*3 + 2] - T2;
        const float* R = rot + i*9;
        float ox = R[0]*px + R[3]*py + R[6]*pz;
        float oy = R[1]*px + R[4]*py + R[7]*pz;
        float oz = R[2]*px + R[5]*py + R[8]*pz;
        feat[1728 + hp]       = ox;
        feat[1728 + 96 + hp]  = oy;
        feat[1728 + 192 + hp] = oz;
        feat[2016 + hp] = sqrtf(ox*ox + oy*oy + oz*oz + 1e-8f);
    }
}

// ---------------------------------------------------------------------------
// Kernel 3c: split-K GEMM partials. Grid (8, 6, KSPLIT).
// ---------------------------------------------------------------------------
__global__ __launch_bounds__(256) void k_final_part(
    const float* __restrict__ ws,
    const float* __restrict__ Whid, const float* __restrict__ Wpair,
    const float* __restrict__ Wpts, const float* __restrict__ Wpn,
    float* __restrict__ fout)
{
    const int m0 = blockIdx.x * 64;
    const int c0 = blockIdx.y * 64;
    const int kc = blockIdx.z;
    const int t  = threadIdx.x;
    const int tc = t & 15;
    const int tm = t >> 4;

    __shared__ float ft[64 * 33];
    __shared__ float wt[32 * 64];

    const float* feat = ws + WS_FEAT;

    float acc[4][4];
#pragma unroll
    for (int r = 0; r < 4; ++r)
#pragma unroll
        for (int u = 0; u < 4; ++u) acc[r][u] = 0.0f;

    const int kbase = kc * KCHUNK;
    for (int k0 = kbase; k0 < kbase + KCHUNK; k0 += 32) {
        const float* W; int r0;
        if (k0 < 192)       { W = Whid;  r0 = k0; }
        else if (k0 < 1728) { W = Wpair; r0 = k0 - 192; }
        else if (k0 < 2016) { W = Wpts;  r0 = k0 - 1728; }
        else                { W = Wpn;   r0 = k0 - 2016; }

        __syncthreads();
        for (int e = t; e < 512; e += 256) {
            int row = e >> 3, kq = e & 7;
            float4 v = *(const float4*)&feat[(size_t)(m0 + row)*NFEAT + k0 + kq*4];
            ft[row*33 + kq*4 + 0] = v.x;
            ft[row*33 + kq*4 + 1] = v.y;
            ft[row*33 + kq*4 + 2] = v.z;
            ft[row*33 + kq*4 + 3] = v.w;
        }
        for (int e = t; e < 512; e += 256) {
            int kk = e >> 4, c4 = e & 15;
            float4 v = *(const float4*)&W[(size_t)(r0 + kk)*C_S + c0 + c4*4];
            *(float4*)&wt[kk*64 + c4*4] = v;
        }
        __syncthreads();

#pragma unroll 8
        for (int kk = 0; kk < 32; ++kk) {
            float4 w = *(const float4*)&wt[kk*64 + tc*4];
            float sv[4];
#pragma unroll
            for (int r = 0; r < 4; ++r) sv[r] = ft[(tm*4 + r)*33 + kk];
#pragma unroll
            for (int r = 0; r < 4; ++r) {
                acc[r][0] += sv[r] * w.x;
                acc[r][1] += sv[r] * w.y;
                acc[r][2] += sv[r] * w.z;
                acc[r][3] += sv[r] * w.w;
            }
        }
    }

#pragma unroll
    for (int r = 0; r < 4; ++r) {
        float4 o = make_float4(acc[r][0], acc[r][1], acc[r][2], acc[r][3]);
        *(float4*)&fout[((size_t)kc*N + m0 + tm*4 + r)*C_S + c0 + tc*4] = o;
    }
}

// ---------------------------------------------------------------------------
// Kernel 3d: reduce split-K partials + bias -> s_out. 768 blocks x 256.
// ---------------------------------------------------------------------------
__global__ __launch_bounds__(256) void k_red(
    const float* __restrict__ fout,
    const float* __restrict__ bhid, const float* __restrict__ bpair,
    const float* __restrict__ bpts, const float* __restrict__ bpn,
    float* __restrict__ s_out)
{
    const int idx = blockIdx.x * 256 + threadIdx.x;
    const int c = idx % C_S;
    float acc = bhid[c] + bpair[c] + bpts[c] + bpn[c];
#pragma unroll
    for (int kc = 0; kc < KSPLIT; ++kc)
        acc += fout[(size_t)kc*N*C_S + idx];
    s_out[idx] = acc;
}

extern "C" void kernel_launch(void* const* d_in, const int* in_sizes, int n_in,
                              void* d_out, int out_size, void* d_ws, size_t ws_size,
                              hipStream_t stream) {
    const float* s     = (const float*)d_in[0];
    const float* z     = (const float*)d_in[1];
    const float* rot   = (const float*)d_in[2];
    const float* trans = (const float*)d_in[3];
    const float* mask  = (const float*)d_in[4];
    const float* Wq    = (const float*)d_in[5];
    const float* bq    = (const float*)d_in[6];
    const float* Wkv   = (const float*)d_in[7];
    const float* bkv   = (const float*)d_in[8];
    const float* Wqp   = (const float*)d_in[9];
    const float* bqp   = (const float*)d_in[10];
    const float* Wkvp  = (const float*)d_in[11];
    const float* bkvp  = (const float*)d_in[12];
    const float* Wb    = (const float*)d_in[13];
    const float* bb    = (const float*)d_in[14];
    const float* hwts  = (const float*)d_in[15];
    const float* Whid  = (const float*)d_in[16];
    const float* bhid  = (const float*)d_in[17];
    const float* Wpair = (const float*)d_in[18];
    const float* bpair = (const float*)d_in[19];
    const float* Wpts  = (const float*)d_in[20];
    const float* bpts  = (const float*)d_in[21];
    const float* Wpn   = (const float*)d_in[22];
    const float* bpn   = (const float*)d_in[23];

    float* out   = (float*)d_out;
    float* s_out = out;                 // 512*384
    float* a_out = out + N*C_S;         // 12*512*512
    float* ws    = (float*)d_ws;

    k_gemm_proj<<<dim3(8, 18), 256, 0, stream>>>(s, Wq, bq, Wkv, bkv, Wqp, bqp,
                                                 Wkvp, bkvp, ws + WS_RAW);
    k_post<<<N, 256, 0, stream>>>(ws + WS_RAW, rot, trans, ws);
    k_logits<<<dim3(N, 4), 256, 0, stream>>>(ws, z, Wb, bb, hwts, mask, a_out);
    k_softmax<<<(H*N)/4, 256, 0, stream>>>(a_out);
    k_av<<<dim3(N, NJC), 256, 0, stream>>>(a_out, ws, z, ws);
    k_feat<<<N, 256, 0, stream>>>(rot, trans, ws);
    k_final_part<<<dim3(8, 6, KSPLIT), 256, 0, stream>>>(ws, Whid, Wpair, Wpts,
                                                         Wpn, ws + WS_FOUT);
    k_red<<<(N*C_S)/256, 256, 0, stream>>>(ws + WS_FOUT, bhid, bpair, bpts, bpn,
                                           s_out);
}

// Round 6
// 193.424 us; speedup vs baseline: 5.9105x; 1.0718x over previous
//
#include <hip/hip_runtime.h>
#include <hip/hip_bf16.h>
#include <cmath>

#define N 512
#define C_S 384
#define C_Z 128
#define C_H 16
#define H 12
#define PQ 4
#define PV 8

#define NJC 4            // j-split chunks in k_av
#define JCHUNK (N / NJC) // 128
#define NPART 2016       // per (i,jc) partial vector: o(192) + o_pt(288) + o_pair(1536)
#define NFEAT 2112       // o(192) + o_pair(1536) + ptsf(288) + pnorm(96)
#define NRAW 1152        // q(192) + kv(384) + qp(144) + kvp(432)
#define KSPLIT 11        // k-chunks in k_final_part (2112 = 11*192)
#define KCHUNK 192

// workspace layout (floats)
#define WS_Q    0
#define WS_K    (WS_Q + N*H*C_H)
#define WS_V    (WS_K + N*H*C_H)
#define WS_QP   (WS_V + N*H*C_H)
#define WS_KP   (WS_QP + N*H*PQ*3)
#define WS_VP   (WS_KP + N*H*PQ*3)
#define WS_PART (WS_VP + N*H*PV*3)            // 512*4*2016 floats
#define WS_FEAT (WS_PART + N*NJC*NPART)       // 512*2112 floats
#define WS_RAW  WS_PART                       // raw[512][1152]; consumed by k_post
#define WS_KT   (WS_PART + 1200000)           // kT[192][512]; live k_post -> k_logits
#define WS_KPT  (WS_KT + 98304)               // kpT[144][512]; live k_post -> k_logits
#define WS_FOUT WS_PART                       // fout[11][512][384]; dead after k_feat

// ---------------------------------------------------------------------------
// Kernel 1a: raw projections as one tiled GEMM.
// ---------------------------------------------------------------------------
__global__ __launch_bounds__(256) void k_gemm_proj(
    const float* __restrict__ s,
    const float* __restrict__ Wq,  const float* __restrict__ bq,
    const float* __restrict__ Wkv, const float* __restrict__ bkv,
    const float* __restrict__ Wqp, const float* __restrict__ bqp,
    const float* __restrict__ Wkvp,const float* __restrict__ bkvp,
    float* __restrict__ raw_out)
{
    const int m0 = blockIdx.x * 64;
    const int c0 = blockIdx.y * 64;
    const int t  = threadIdx.x;
    const int tc = t & 15;
    const int tm = t >> 4;

    __shared__ float st[64 * 33];
    __shared__ float wt[32 * 64];

    float acc[4][4];
#pragma unroll
    for (int u = 0; u < 4; ++u) {
        int col = c0 + tc*4 + u;
        const float* b; int cb;
        if (col < 192)      { b = bq;   cb = 0; }
        else if (col < 576) { b = bkv;  cb = 192; }
        else if (col < 720) { b = bqp;  cb = 576; }
        else                { b = bkvp; cb = 720; }
        float bv = b[col - cb];
#pragma unroll
        for (int r = 0; r < 4; ++r) acc[r][u] = bv;
    }

    for (int k0 = 0; k0 < C_S; k0 += 32) {
        __syncthreads();
        for (int e = t; e < 512; e += 256) {
            int row = e >> 3, kq = e & 7;
            float4 v = *(const float4*)&s[(size_t)(m0 + row)*C_S + k0 + kq*4];
            st[row*33 + kq*4 + 0] = v.x;
            st[row*33 + kq*4 + 1] = v.y;
            st[row*33 + kq*4 + 2] = v.z;
            st[row*33 + kq*4 + 3] = v.w;
        }
        for (int e = t; e < 512; e += 256) {
            int kk = e >> 4, c4 = e & 15;
            int col = c0 + c4*4;
            const float* W; int ncol, cb;
            if (col < 192)      { W = Wq;   ncol = 192; cb = 0; }
            else if (col < 576) { W = Wkv;  ncol = 384; cb = 192; }
            else if (col < 720) { W = Wqp;  ncol = 144; cb = 576; }
            else                { W = Wkvp; ncol = 432; cb = 720; }
            float4 v = *(const float4*)&W[(size_t)(k0 + kk)*ncol + (col - cb)];
            *(float4*)&wt[kk*64 + c4*4] = v;
        }
        __syncthreads();

#pragma unroll 8
        for (int kk = 0; kk < 32; ++kk) {
            float4 w = *(const float4*)&wt[kk*64 + tc*4];
            float sv[4];
#pragma unroll
            for (int r = 0; r < 4; ++r) sv[r] = st[(tm*4 + r)*33 + kk];
#pragma unroll
            for (int r = 0; r < 4; ++r) {
                acc[r][0] += sv[r] * w.x;
                acc[r][1] += sv[r] * w.y;
                acc[r][2] += sv[r] * w.z;
                acc[r][3] += sv[r] * w.w;
            }
        }
    }

#pragma unroll
    for (int r = 0; r < 4; ++r) {
        float4 o = make_float4(acc[r][0], acc[r][1], acc[r][2], acc[r][3]);
        *(float4*)&raw_out[(size_t)(m0 + tm*4 + r)*NRAW + c0 + tc*4] = o;
    }
}

// ---------------------------------------------------------------------------
// Kernel 1b: rotary + rigid-frame point transforms. One block per residue n.
// Also writes transposed kT[h*16+c][n] and kpT[h*12+p*3+ic][n] for coalesced
// access in k_logits.
// ---------------------------------------------------------------------------
__global__ __launch_bounds__(256) void k_post(
    const float* __restrict__ raw_in, const float* __restrict__ rot,
    const float* __restrict__ trans, float* __restrict__ ws)
{
    const int n = blockIdx.x;
    const int t = threadIdx.x;
    __shared__ float raw[NRAW];

    for (int idx = t; idx < NRAW; idx += 256) raw[idx] = raw_in[(size_t)n*NRAW + idx];
    __syncthreads();

    float R[9], T[3];
#pragma unroll
    for (int u = 0; u < 9; ++u) R[u] = rot[n*9 + u];
#pragma unroll
    for (int u = 0; u < 3; ++u) T[u] = trans[n*3 + u];

    float* q   = ws + WS_Q;
    float* v   = ws + WS_V;
    float* qp  = ws + WS_QP;
    float* vp  = ws + WS_VP;
    float* kT  = ws + WS_KT;
    float* kpT = ws + WS_KPT;

    for (int idx = t; idx < 1152; idx += 256) {
        if (idx < 192) {
            int h = idx >> 4, c = idx & 15;
            float val;
            if (c < 8) {
                int f = c >> 1;
                float x1 = raw[h*16 + 2*f];
                float x2 = raw[h*16 + 2*f + 1];
                float ang = (float)n * powf(10000.0f, -(float)(2*f) / 8.0f);
                float cs = cosf(ang), sn = sinf(ang);
                val = (c & 1) ? (x1*sn + x2*cs) : (x1*cs - x2*sn);
            } else {
                val = raw[h*16 + c];
            }
            q[n*192 + idx] = val;
        } else if (idx < 384) {
            int o = idx - 192, h = o >> 4, c = o & 15;
            float val;
            if (c < 8) {
                int f = c >> 1;
                float x1 = raw[192 + h*32 + 2*f];
                float x2 = raw[192 + h*32 + 2*f + 1];
                float ang = (float)n * powf(10000.0f, -(float)(2*f) / 8.0f);
                float cs = cosf(ang), sn = sinf(ang);
                val = (c & 1) ? (x1*sn + x2*cs) : (x1*cs - x2*sn);
            } else {
                val = raw[192 + h*32 + c];
            }
            kT[(size_t)o*N + n] = val;
        } else if (idx < 576) {
            int o = idx - 384, h = o >> 4, c = o & 15;
            v[n*192 + o] = raw[192 + h*32 + 16 + c];
        } else if (idx < 720) {
            int o = idx - 576;
            int hp = o / 3, ic = o - hp*3;
            float acc = T[ic];
#pragma unroll
            for (int j = 0; j < 3; ++j) acc += R[ic*3 + j] * raw[576 + j*48 + hp];
            qp[n*144 + o] = acc;
        } else {
            int o = idx - 720;
            int hp = o / 3, ic = o - hp*3;
            int h = hp / 12, p = hp - h*12;
            float acc = T[ic];
#pragma unroll
            for (int j = 0; j < 3; ++j) acc += R[ic*3 + j] * raw[720 + j*144 + hp];
            if (p < PQ) kpT[(size_t)(h*12 + p*3 + ic)*N + n] = acc;
            else        vp[n*(H*PV*3) + (h*PV + (p - PQ))*3 + ic] = acc;
        }
    }
}

// ---------------------------------------------------------------------------
// Kernel 2a: raw logits. Grid (N, 8): block = (i, 64-j tile). One barrier.
// Lane = j (0..63); wave w owns heads {3w, 3w+1, 3w+2} (wave-uniform h ->
// Wb reads are LDS broadcasts). z tile staged once at stride 132 (b128
// conflict-free). qkd computed in registers from transposed kT/kpT.
// ---------------------------------------------------------------------------
__global__ __launch_bounds__(256) void k_logits(
    const float* __restrict__ ws, const float* __restrict__ z,
    const float* __restrict__ Wb, const float* __restrict__ bb,
    const float* __restrict__ hwts, const float* __restrict__ mask,
    float* __restrict__ a_out)
{
    const int i  = blockIdx.x;
    const int j0 = blockIdx.y * 64;
    const int t  = threadIdx.x;
    const int j  = t & 63;
    const int w  = t >> 6;
    const int jg = j0 + j;

    __shared__ float zt[64*132];     // 33 KB, stride 132
    __shared__ float wbL[H*128];     // [h][c]
    __shared__ float qi[192];
    __shared__ float qpi[144];
    __shared__ float hw_eff[12], bbs[12];

    const float* q   = ws + WS_Q;
    const float* qp  = ws + WS_QP;
    const float* kT  = ws + WS_KT;
    const float* kpT = ws + WS_KPT;

    // setup + stage (single barrier covers all)
    for (int idx = t; idx < H*C_Z; idx += 256) {
        int h = idx >> 7, c = idx & 127;
        wbL[h*128 + c] = Wb[c*H + h];
    }
    if (t < 192) qi[t]  = q[i*192 + t];
    if (t < 144) qpi[t] = qp[i*144 + t];
    if (t < 12) {
        hw_eff[t] = log1pf(expf(hwts[t])) * sqrtf(1.0f / 54.0f);
        bbs[t]    = bb[t];
    }
    for (int e = t; e < 2048; e += 256) {
        int row = e >> 5, cq = e & 31;
        float4 v4 = *(const float4*)&z[(((size_t)i*N) + j0 + row)*C_Z + cq*4];
        *(float4*)&zt[row*132 + cq*4] = v4;
    }
    __syncthreads();

    const float c1 = sqrtf(1.0f / 48.0f);
    const float c2 = sqrtf(1.0f / 3.0f);
    const float mterm = 100000.0f * (mask[i] * mask[jg] - 1.0f);

    // phase 1: qkd per (j, 3h) in registers — all kT/kpT loads lane-coalesced
    float qkd[3];
#pragma unroll
    for (int u = 0; u < 3; ++u) {
        const int h = 3*w + u;
        float qk = 0.0f;
#pragma unroll
        for (int c = 0; c < 16; ++c)
            qk += qi[h*16 + c] * kT[(size_t)(h*16 + c)*N + jg];
        float d2s = 0.0f;
#pragma unroll
        for (int e = 0; e < 12; ++e) {
            float d = qpi[h*12 + e] - kpT[(size_t)(h*12 + e)*N + jg];
            d2s += d*d;
        }
        qkd[u] = c1*qk - 0.5f*hw_eff[h]*d2s + mterm + c2*bbs[h];
    }

    // phase 2: z@Wb, h wave-uniform
    float acc[3] = {0.0f, 0.0f, 0.0f};
    const int h0 = 3*w;
#pragma unroll 8
    for (int c4 = 0; c4 < 32; ++c4) {
        float4 zv = *(const float4*)&zt[j*132 + c4*4];
#pragma unroll
        for (int u = 0; u < 3; ++u) {
            float4 wb = *(const float4*)&wbL[(h0 + u)*128 + c4*4];
            acc[u] += zv.x*wb.x + zv.y*wb.y + zv.z*wb.z + zv.w*wb.w;
        }
    }

#pragma unroll
    for (int u = 0; u < 3; ++u)
        a_out[((size_t)(h0 + u)*N + i)*N + jg] = qkd[u] + c2*acc[u];
}

// ---------------------------------------------------------------------------
// Kernel 2b: in-place softmax over rows of a_out[6144][512]. One wave per row.
// ---------------------------------------------------------------------------
__global__ __launch_bounds__(256) void k_softmax(float* __restrict__ a)
{
    const int row  = blockIdx.x*4 + (threadIdx.x >> 6);
    const int lane = threadIdx.x & 63;
    float* r = a + (size_t)row * N;

    float v[8];
    float m = -1e30f;
#pragma unroll
    for (int u = 0; u < 8; ++u) { v[u] = r[lane + 64*u]; m = fmaxf(m, v[u]); }
#pragma unroll
    for (int off = 32; off; off >>= 1) m = fmaxf(m, __shfl_xor(m, off));
    float ssum = 0.0f;
#pragma unroll
    for (int u = 0; u < 8; ++u) { v[u] = expf(v[u] - m); ssum += v[u]; }
#pragma unroll
    for (int off = 32; off; off >>= 1) ssum += __shfl_xor(ssum, off);
    float inv = 1.0f / ssum;
#pragma unroll
    for (int u = 0; u < 8; ++u) r[lane + 64*u] = v[u] * inv;
}

// ---------------------------------------------------------------------------
// Kernel 3a: partial o / o_pt / o_pair over a j-chunk. Grid (N, NJC).
// ---------------------------------------------------------------------------
__global__ __launch_bounds__(256) void k_av(
    const float* __restrict__ a_full, const float* __restrict__ ws_ro,
    const float* __restrict__ z, float* __restrict__ ws)
{
    const int i  = blockIdx.x;
    const int jc = blockIdx.y;
    const int j0 = jc * JCHUNK;
    const int t  = threadIdx.x;

    __shared__ float a_s[H*JCHUNK];

    const float* v  = ws_ro + WS_V;
    const float* vp = ws_ro + WS_VP;
    float* part = ws + WS_PART + ((size_t)i*NJC + jc)*NPART;

    for (int e = t; e < H*JCHUNK; e += 256) {
        int h = e >> 7, jj = e & (JCHUNK-1);
        a_s[e] = a_full[((size_t)h*N + i)*N + j0 + jj];
    }
    __syncthreads();

    for (int idx = t; idx < 480; idx += 256) {
        float acc = 0.0f;
        if (idx < 192) {
            int h = idx >> 4;
            const float* vv = v + (size_t)j0*192 + idx;
            const float* ar = &a_s[h*JCHUNK];
#pragma unroll 4
            for (int jj = 0; jj < JCHUNK; ++jj) acc += ar[jj] * vv[(size_t)jj*192];
        } else {
            int o = idx - 192;
            int h = (o/3) >> 3;
            const float* vv = vp + (size_t)j0*288 + o;
            const float* ar = &a_s[h*JCHUNK];
#pragma unroll 4
            for (int jj = 0; jj < JCHUNK; ++jj) acc += ar[jj] * vv[(size_t)jj*288];
        }
        part[idx] = acc;
    }

    {
        const int c  = t & 127;
        const int hb = t >> 7;
        float acc[6];
#pragma unroll
        for (int u = 0; u < 6; ++u) acc[u] = 0.0f;
        const float* zi = z + ((size_t)i*N + j0)*C_Z + c;
#pragma unroll 4
        for (int jj = 0; jj < JCHUNK; ++jj) {
            float zv = zi[(size_t)jj*C_Z];
#pragma unroll
            for (int u = 0; u < 6; ++u) acc[u] += a_s[(hb + 2*u)*JCHUNK + jj] * zv;
        }
#pragma unroll
        for (int u = 0; u < 6; ++u) part[480 + (hb + 2*u)*C_Z + c] = acc[u];
    }
}

// ---------------------------------------------------------------------------
// Kernel 3b: reduce partials, inverse-frame rotation, norms -> feat[i][2112].
// ---------------------------------------------------------------------------
__global__ __launch_bounds__(256) void k_feat(
    const float* __restrict__ rot, const float* __restrict__ trans,
    float* __restrict__ ws)
{
    const int i = blockIdx.x;
    const int t = threadIdx.x;

    __shared__ float vec[NPART];

    const float* part = ws + WS_PART + (size_t)i*NJC*NPART;
    float* feat = ws + WS_FEAT + (size_t)i*NFEAT;

    for (int e = t; e < NPART; e += 256) {
        float acc = 0.0f;
#pragma unroll
        for (int jc = 0; jc < NJC; ++jc) acc += part[(size_t)jc*NPART + e];
        vec[e] = acc;
    }
    __syncthreads();

    for (int e = t; e < NPART; e += 256) {
        if (e < 192)       feat[e] = vec[e];
        else if (e >= 480) feat[192 + (e - 480)] = vec[e];
    }

    if (t < H*PV) {
        const int hp = t;
        float T0 = trans[i*3+0], T1 = trans[i*3+1], T2 = trans[i*3+2];
        float px = vec[192 + hp*3 + 0] - T0;
        float py = vec[192 + hp*3 + 1] - T1;
        float pz = vec[192 + hp*3 + 2] - T2;
        const float* R = rot + i*9;
        float ox = R[0]*px + R[3]*py + R[6]*pz;
        float oy = R[1]*px + R[4]*py + R[7]*pz;
        float oz = R[2]*px + R[5]*py + R[8]*pz;
        feat[1728 + hp]       = ox;
        feat[1728 + 96 + hp]  = oy;
        feat[1728 + 192 + hp] = oz;
        feat[2016 + hp] = sqrtf(ox*ox + oy*oy + oz*oz + 1e-8f);
    }
}

// ---------------------------------------------------------------------------
// Kernel 3c: split-K GEMM partials. Grid (8, 6, KSPLIT).
// ---------------------------------------------------------------------------
__global__ __launch_bounds__(256) void k_final_part(
    const float* __restrict__ ws,
    const float* __restrict__ Whid, const float* __restrict__ Wpair,
    const float* __restrict__ Wpts, const float* __restrict__ Wpn,
    float* __restrict__ fout)
{
    const int m0 = blockIdx.x * 64;
    const int c0 = blockIdx.y * 64;
    const int kc = blockIdx.z;
    const int t  = threadIdx.x;
    const int tc = t & 15;
    const int tm = t >> 4;

    __shared__ float ft[64 * 33];
    __shared__ float wt[32 * 64];

    const float* feat = ws + WS_FEAT;

    float acc[4][4];
#pragma unroll
    for (int r = 0; r < 4; ++r)
#pragma unroll
        for (int u = 0; u < 4; ++u) acc[r][u] = 0.0f;

    const int kbase = kc * KCHUNK;
    for (int k0 = kbase; k0 < kbase + KCHUNK; k0 += 32) {
        const float* W; int r0;
        if (k0 < 192)       { W = Whid;  r0 = k0; }
        else if (k0 < 1728) { W = Wpair; r0 = k0 - 192; }
        else if (k0 < 2016) { W = Wpts;  r0 = k0 - 1728; }
        else                { W = Wpn;   r0 = k0 - 2016; }

        __syncthreads();
        for (int e = t; e < 512; e += 256) {
            int row = e >> 3, kq = e & 7;
            float4 v = *(const float4*)&feat[(size_t)(m0 + row)*NFEAT + k0 + kq*4];
            ft[row*33 + kq*4 + 0] = v.x;
            ft[row*33 + kq*4 + 1] = v.y;
            ft[row*33 + kq*4 + 2] = v.z;
            ft[row*33 + kq*4 + 3] = v.w;
        }
        for (int e = t; e < 512; e += 256) {
            int kk = e >> 4, c4 = e & 15;
            float4 v = *(const float4*)&W[(size_t)(r0 + kk)*C_S + c0 + c4*4];
            *(float4*)&wt[kk*64 + c4*4] = v;
        }
        __syncthreads();

#pragma unroll 8
        for (int kk = 0; kk < 32; ++kk) {
            float4 w = *(const float4*)&wt[kk*64 + tc*4];
            float sv[4];
#pragma unroll
            for (int r = 0; r < 4; ++r) sv[r] = ft[(tm*4 + r)*33 + kk];
#pragma unroll
            for (int r = 0; r < 4; ++r) {
                acc[r][0] += sv[r] * w.x;
                acc[r][1] += sv[r] * w.y;
                acc[r][2] += sv[r] * w.z;
                acc[r][3] += sv[r] * w.w;
            }
        }
    }

#pragma unroll
    for (int r = 0; r < 4; ++r) {
        float4 o = make_float4(acc[r][0], acc[r][1], acc[r][2], acc[r][3]);
        *(float4*)&fout[((size_t)kc*N + m0 + tm*4 + r)*C_S + c0 + tc*4] = o;
    }
}

// ---------------------------------------------------------------------------
// Kernel 3d: reduce split-K partials + bias -> s_out. 768 blocks x 256.
// ---------------------------------------------------------------------------
__global__ __launch_bounds__(256) void k_red(
    const float* __restrict__ fout,
    const float* __restrict__ bhid, const float* __restrict__ bpair,
    const float* __restrict__ bpts, const float* __restrict__ bpn,
    float* __restrict__ s_out)
{
    const int idx = blockIdx.x * 256 + threadIdx.x;
    const int c = idx % C_S;
    float acc = bhid[c] + bpair[c] + bpts[c] + bpn[c];
#pragma unroll
    for (int kc = 0; kc < KSPLIT; ++kc)
        acc += fout[(size_t)kc*N*C_S + idx];
    s_out[idx] = acc;
}

extern "C" void kernel_launch(void* const* d_in, const int* in_sizes, int n_in,
                              void* d_out, int out_size, void* d_ws, size_t ws_size,
                              hipStream_t stream) {
    const float* s     = (const float*)d_in[0];
    const float* z     = (const float*)d_in[1];
    const float* rot   = (const float*)d_in[2];
    const float* trans = (const float*)d_in[3];
    const float* mask  = (const float*)d_in[4];
    const float* Wq    = (const float*)d_in[5];
    const float* bq    = (const float*)d_in[6];
    const float* Wkv   = (const float*)d_in[7];
    const float* bkv   = (const float*)d_in[8];
    const float* Wqp   = (const float*)d_in[9];
    const float* bqp   = (const float*)d_in[10];
    const float* Wkvp  = (const float*)d_in[11];
    const float* bkvp  = (const float*)d_in[12];
    const float* Wb    = (const float*)d_in[13];
    const float* bb    = (const float*)d_in[14];
    const float* hwts  = (const float*)d_in[15];
    const float* Whid  = (const float*)d_in[16];
    const float* bhid  = (const float*)d_in[17];
    const float* Wpair = (const float*)d_in[18];
    const float* bpair = (const float*)d_in[19];
    const float* Wpts  = (const float*)d_in[20];
    const float* bpts  = (const float*)d_in[21];
    const float* Wpn   = (const float*)d_in[22];
    const float* bpn   = (const float*)d_in[23];

    float* out   = (float*)d_out;
    float* s_out = out;                 // 512*384
    float* a_out = out + N*C_S;         // 12*512*512
    float* ws    = (float*)d_ws;

    k_gemm_proj<<<dim3(8, 18), 256, 0, stream>>>(s, Wq, bq, Wkv, bkv, Wqp, bqp,
                                                 Wkvp, bkvp, ws + WS_RAW);
    k_post<<<N, 256, 0, stream>>>(ws + WS_RAW, rot, trans, ws);
    k_logits<<<dim3(N, 8), 256, 0, stream>>>(ws, z, Wb, bb, hwts, mask, a_out);
    k_softmax<<<(H*N)/4, 256, 0, stream>>>(a_out);
    k_av<<<dim3(N, NJC), 256, 0, stream>>>(a_out, ws, z, ws);
    k_feat<<<N, 256, 0, stream>>>(rot, trans, ws);
    k_final_part<<<dim3(8, 6, KSPLIT), 256, 0, stream>>>(ws, Whid, Wpair, Wpts,
                                                         Wpn, ws + WS_FOUT);
    k_red<<<(N*C_S)/256, 256, 0, stream>>>(ws + WS_FOUT, bhid, bpair, bpts, bpn,
                                           s_out);
}